// Round 8
// baseline (843.665 us; speedup 1.0000x reference)
//
#include <hip/hip_runtime.h>
#include <stdint.h>

#define D 2048
#define LSEQ 2048
#define BATCH 4
#define BL (BATCH * LSEQ)   // 8192 rows
#define NSLOT 16
#define NHEAD 32
#define HDIM 64
#define EPSV 1e-6f

typedef __attribute__((ext_vector_type(8))) short bf16x8;
typedef __attribute__((ext_vector_type(4))) float f32x4;

static __device__ __forceinline__ ushort f2bf(float f) {
    uint32_t u = __float_as_uint(f);
    u += 0x7fffu + ((u >> 16) & 1u);   // RNE
    return (ushort)(u >> 16);
}

static __device__ __forceinline__ float wave_sum(float v) {
#pragma unroll
    for (int off = 32; off > 0; off >>= 1) v += __shfl_xor(v, off, 64);
    return v;
}

static __device__ __forceinline__ void gl_lds16(const void* g, void* l) {
    __builtin_amdgcn_global_load_lds(
        (__attribute__((address_space(1))) uint32_t*)(uintptr_t)g,
        (__attribute__((address_space(3))) uint32_t*)(uint32_t)(uintptr_t)l,
        16, 0, 0);
}

// ---------------- weight convert f32 -> bf16 ----------------
__global__ __launch_bounds__(256) void conv_bf16_kernel(const float4* __restrict__ src,
                                                        ushort* __restrict__ dst, int n4) {
    int i = blockIdx.x * 256 + threadIdx.x;
    int stride = gridDim.x * 256;
    for (; i < n4; i += stride) {
        float4 v = src[i];
        uint2 o;
        o.x = (uint)f2bf(v.x) | ((uint)f2bf(v.y) << 16);
        o.y = (uint)f2bf(v.z) | ((uint)f2bf(v.w) << 16);
        *(uint2*)(dst + (size_t)i * 4) = o;
    }
}

// ---------------- logits v4: 4 rows/block, BIT-EXACT to the R4-passing kernel ----
// DO NOT change any arithmetic here: logits bits feed top-k (an order-statistic
// discontinuity); R5 failed from a 1e-7-level summation-order change.
__global__ __launch_bounds__(256) void logits_kernel(
    const float* __restrict__ x, const float* __restrict__ cw,
    const float* __restrict__ cb, const float* __restrict__ wpre,
    float* __restrict__ logits_t) {
    int blk = blockIdx.x;              // 2048 blocks, 4 rows each
    int b = blk >> 9;                  // 512 blocks per batch
    int l0 = (blk & 511) << 2;
    int tid = threadIdx.x;
    int i0 = tid * 8;
    float4 w0 = *(const float4*)(wpre + i0);
    float4 w1 = *(const float4*)(wpre + i0 + 4);
    float wv[8] = {w0.x, w0.y, w0.z, w0.w, w1.x, w1.y, w1.z, w1.w};
    float xw[4][8];
    float ss[4];
#pragma unroll
    for (int r = 0; r < 4; ++r) {
        const float* xr = x + ((size_t)(b * LSEQ + l0 + r)) * D;
        float4 a0 = *(const float4*)(xr + i0);
        float4 a1 = *(const float4*)(xr + i0 + 4);
        float xv[8] = {a0.x, a0.y, a0.z, a0.w, a1.x, a1.y, a1.z, a1.w};
        float s0 = 0.f;
#pragma unroll
        for (int j = 0; j < 8; ++j) { s0 += xv[j] * xv[j]; xw[r][j] = xv[j] * wv[j]; }
        ss[r] = s0;
    }
    float acc[NSLOT][4];
#pragma unroll
    for (int s = 0; s < NSLOT; ++s) {
        const float* cwr = cw + (size_t)s * D + i0;
        float4 c0 = *(const float4*)(cwr);
        float4 c1 = *(const float4*)(cwr + 4);
#pragma unroll
        for (int r = 0; r < 4; ++r)
            acc[s][r] = xw[r][0] * c0.x + xw[r][1] * c0.y + xw[r][2] * c0.z + xw[r][3] * c0.w +
                        xw[r][4] * c1.x + xw[r][5] * c1.y + xw[r][6] * c1.z + xw[r][7] * c1.w;
    }
#pragma unroll
    for (int r = 0; r < 4; ++r) ss[r] = wave_sum(ss[r]);
#pragma unroll
    for (int s = 0; s < NSLOT; ++s)
#pragma unroll
        for (int r = 0; r < 4; ++r) acc[s][r] = wave_sum(acc[s][r]);
    __shared__ float red[4][NSLOT][4];
    __shared__ float redss[4][4];
    int lane = tid & 63, w = tid >> 6;
    if (lane == 0) {
#pragma unroll
        for (int r = 0; r < 4; ++r) redss[w][r] = ss[r];
#pragma unroll
        for (int s = 0; s < NSLOT; ++s)
#pragma unroll
            for (int r = 0; r < 4; ++r) red[w][s][r] = acc[s][r];
    }
    __syncthreads();
    if (tid < 64) {
        int s = tid >> 2, r = tid & 3;
        float tot = red[0][s][r] + red[1][s][r] + red[2][s][r] + red[3][s][r];
        float s2 = redss[0][r] + redss[1][r] + redss[2][r] + redss[3][r];
        float rsq = 1.0f / sqrtf(s2 * (1.0f / (float)D) + EPSV);
        logits_t[((size_t)(b * NSLOT + s)) * LSEQ + l0 + r] = tot * rsq + cb[s];
    }
}

// ---------------- top-4 + softmax + weighted row gather (xbar, bf16) ----------------
__global__ __launch_bounds__(256) void topk_xbar_kernel(
    const float* __restrict__ logits_t, const float* __restrict__ x,
    ushort* __restrict__ xbar_b) {
    int bs = blockIdx.x;
    int b = bs >> 4;
    const float* lr = logits_t + (size_t)bs * LSEQ;
    int tid = threadIdx.x, lane = tid & 63, w = tid >> 6;
    __shared__ float rv[4];
    __shared__ int ri[4];
    __shared__ float selv[4];
    __shared__ int seli[4];
    int i0 = tid * 8;
    float myv[8];
#pragma unroll
    for (int j = 0; j < 8; ++j) myv[j] = lr[i0 + j];
    int chosen[4];
    for (int p = 0; p < 4; ++p) {
        float bv = -3.4e38f;
        int bi = 0x7fffffff;
#pragma unroll
        for (int j = 0; j < 8; ++j) {
            int i = i0 + j;
            bool skip = false;
            for (int q = 0; q < p; ++q) skip = skip || (i == chosen[q]);
            float v = myv[j];
            if (!skip && (v > bv || (v == bv && i < bi))) { bv = v; bi = i; }
        }
#pragma unroll
        for (int off = 1; off < 64; off <<= 1) {
            float ov = __shfl_xor(bv, off, 64);
            int oi = __shfl_xor(bi, off, 64);
            if (ov > bv || (ov == bv && oi < bi)) { bv = ov; bi = oi; }
        }
        if (lane == 0) { rv[w] = bv; ri[w] = bi; }
        __syncthreads();
        if (tid == 0) {
            float fv = rv[0];
            int fi = ri[0];
            for (int q = 1; q < 4; ++q)
                if (rv[q] > fv || (rv[q] == fv && ri[q] < fi)) { fv = rv[q]; fi = ri[q]; }
            selv[p] = fv;
            seli[p] = fi;
        }
        __syncthreads();
        chosen[p] = seli[p];
    }
    float vals[4];
#pragma unroll
    for (int p = 0; p < 4; ++p) vals[p] = selv[p];
    float mx = vals[0];   // first pick is the max
    float e[4], den = 0.f;
#pragma unroll
    for (int p = 0; p < 4; ++p) { e[p] = expf(vals[p] - mx); den += e[p]; }
    float inv = 1.0f / den;
    const float* xr0 = x + ((size_t)b * LSEQ + chosen[0]) * D;
    const float* xr1 = x + ((size_t)b * LSEQ + chosen[1]) * D;
    const float* xr2 = x + ((size_t)b * LSEQ + chosen[2]) * D;
    const float* xr3 = x + ((size_t)b * LSEQ + chosen[3]) * D;
    float s[8];
#pragma unroll
    for (int j = 0; j < 8; ++j) {
        int i = i0 + j;
        s[j] = (e[0] * xr0[i] + e[1] * xr1[i] + e[2] * xr2[i] + e[3] * xr3[i]) * inv;
    }
    uint4 o;
    o.x = (uint)f2bf(s[0]) | ((uint)f2bf(s[1]) << 16);
    o.y = (uint)f2bf(s[2]) | ((uint)f2bf(s[3]) << 16);
    o.z = (uint)f2bf(s[4]) | ((uint)f2bf(s[5]) << 16);
    o.w = (uint)f2bf(s[6]) | ((uint)f2bf(s[7]) << 16);
    *(uint4*)(xbar_b + (size_t)bs * D + i0) = o;
}

// ---------------- ws = rms(ws_prev + written) (+bf16 copy) ----------------
__global__ __launch_bounds__(256) void ws_update_kernel(
    const float* __restrict__ written, const float* __restrict__ ws_prev,
    const float* __restrict__ workspace0, int first,
    const float* __restrict__ wpost, float* __restrict__ ws_out,
    ushort* __restrict__ ws_b) {
    int bs = blockIdx.x;
    int s = bs & (NSLOT - 1);
    int tid = threadIdx.x;
    int i0 = tid * 8;
    const float* prev = first ? (workspace0 + (size_t)s * D) : (ws_prev + (size_t)bs * D);
    const float* wr = written + (size_t)bs * D;
    float4 p0 = *(const float4*)(prev + i0);
    float4 p1 = *(const float4*)(prev + i0 + 4);
    float4 q0 = *(const float4*)(wr + i0);
    float4 q1 = *(const float4*)(wr + i0 + 4);
    float t[8] = {p0.x + q0.x, p0.y + q0.y, p0.z + q0.z, p0.w + q0.w,
                  p1.x + q1.x, p1.y + q1.y, p1.z + q1.z, p1.w + q1.w};
    float ss = 0.f;
#pragma unroll
    for (int j = 0; j < 8; ++j) ss += t[j] * t[j];
    ss = wave_sum(ss);
    __shared__ float sb[4];
    if ((tid & 63) == 0) sb[tid >> 6] = ss;
    __syncthreads();
    ss = sb[0] + sb[1] + sb[2] + sb[3];
    float rsq = 1.0f / sqrtf(ss * (1.0f / (float)D) + EPSV);
    float4 w0 = *(const float4*)(wpost + i0);
    float4 w1 = *(const float4*)(wpost + i0 + 4);
    float wv[8] = {w0.x, w0.y, w0.z, w0.w, w1.x, w1.y, w1.z, w1.w};
    float o[8];
#pragma unroll
    for (int j = 0; j < 8; ++j) o[j] = t[j] * rsq * wv[j];
    float4 r0 = {o[0], o[1], o[2], o[3]};
    float4 r1 = {o[4], o[5], o[6], o[7]};
    *(float4*)(ws_out + (size_t)bs * D + i0) = r0;
    *(float4*)(ws_out + (size_t)bs * D + i0 + 4) = r1;
    uint4 ob;
    ob.x = (uint)f2bf(o[0]) | ((uint)f2bf(o[1]) << 16);
    ob.y = (uint)f2bf(o[2]) | ((uint)f2bf(o[3]) << 16);
    ob.z = (uint)f2bf(o[4]) | ((uint)f2bf(o[5]) << 16);
    ob.w = (uint)f2bf(o[6]) | ((uint)f2bf(o[7]) << 16);
    *(uint4*)(ws_b + (size_t)bs * D + i0) = ob;
}

// ---------------- x = rms(x + attn_out) (+bf16 copy) ----------------
__global__ __launch_bounds__(256) void resid_rms_kernel(
    const float* __restrict__ x_src, const float* __restrict__ ao,
    const float* __restrict__ wpost, float* __restrict__ x_dst,
    ushort* __restrict__ xb) {
    int row = blockIdx.x;
    int tid = threadIdx.x;
    int i0 = tid * 8;
    const float* xr = x_src + (size_t)row * D;
    const float* ar = ao + (size_t)row * D;
    float4 p0 = *(const float4*)(xr + i0);
    float4 p1 = *(const float4*)(xr + i0 + 4);
    float4 q0 = *(const float4*)(ar + i0);
    float4 q1 = *(const float4*)(ar + i0 + 4);
    float t[8] = {p0.x + q0.x, p0.y + q0.y, p0.z + q0.z, p0.w + q0.w,
                  p1.x + q1.x, p1.y + q1.y, p1.z + q1.z, p1.w + q1.w};
    float ss = 0.f;
#pragma unroll
    for (int j = 0; j < 8; ++j) ss += t[j] * t[j];
    ss = wave_sum(ss);
    __shared__ float sb[4];
    if ((tid & 63) == 0) sb[tid >> 6] = ss;
    __syncthreads();
    ss = sb[0] + sb[1] + sb[2] + sb[3];
    float rsq = 1.0f / sqrtf(ss * (1.0f / (float)D) + EPSV);
    float4 w0 = *(const float4*)(wpost + i0);
    float4 w1 = *(const float4*)(wpost + i0 + 4);
    float wv[8] = {w0.x, w0.y, w0.z, w0.w, w1.x, w1.y, w1.z, w1.w};
    float o[8];
#pragma unroll
    for (int j = 0; j < 8; ++j) o[j] = t[j] * rsq * wv[j];
    float4 r0 = {o[0], o[1], o[2], o[3]};
    float4 r1 = {o[4], o[5], o[6], o[7]};
    *(float4*)(x_dst + (size_t)row * D + i0) = r0;
    *(float4*)(x_dst + (size_t)row * D + i0 + 4) = r1;
    uint4 ob;
    ob.x = (uint)f2bf(o[0]) | ((uint)f2bf(o[1]) << 16);
    ob.y = (uint)f2bf(o[2]) | ((uint)f2bf(o[3]) << 16);
    ob.z = (uint)f2bf(o[4]) | ((uint)f2bf(o[5]) << 16);
    ob.w = (uint)f2bf(o[6]) | ((uint)f2bf(o[7]) << 16);
    *(uint4*)(xb + (size_t)row * D + i0) = ob;
}

// ---------------- attention v6: 8 lanes per row, registers only ----------------
__global__ __launch_bounds__(256) void attn_kernel(
    const ushort* __restrict__ qb, const ushort* __restrict__ kb,
    const ushort* __restrict__ vb, ushort* __restrict__ ctxb) {
    int g = blockIdx.x * 256 + threadIdx.x;
    int w = g >> 6;                     // global wave id
    int lane = g & 63;
    int b = w >> 13;                    // 8192 waves per batch
    int h = (w >> 8) & 31;
    int lt = w & 255;
    int l = lt * 8 + (lane >> 3);
    int d0 = (lane & 7) * 8;
    uint4 qv = *(const uint4*)(qb + ((size_t)(b * LSEQ + l)) * D + h * HDIM + d0);
    float qf[8];
    qf[0] = __uint_as_float(qv.x << 16);
    qf[1] = __uint_as_float(qv.x & 0xffff0000u);
    qf[2] = __uint_as_float(qv.y << 16);
    qf[3] = __uint_as_float(qv.y & 0xffff0000u);
    qf[4] = __uint_as_float(qv.z << 16);
    qf[5] = __uint_as_float(qv.z & 0xffff0000u);
    qf[6] = __uint_as_float(qv.w << 16);
    qf[7] = __uint_as_float(qv.w & 0xffff0000u);
    const ushort* kbase = kb + (((size_t)(b * NHEAD + h)) * NSLOT) * HDIM + d0;
    float p[NSLOT];
#pragma unroll
    for (int s = 0; s < NSLOT; ++s) {
        uint4 kc = *(const uint4*)(kbase + s * HDIM);
        float a;
        a  = qf[0] * __uint_as_float(kc.x << 16);
        a += qf[1] * __uint_as_float(kc.x & 0xffff0000u);
        a += qf[2] * __uint_as_float(kc.y << 16);
        a += qf[3] * __uint_as_float(kc.y & 0xffff0000u);
        a += qf[4] * __uint_as_float(kc.z << 16);
        a += qf[5] * __uint_as_float(kc.z & 0xffff0000u);
        a += qf[6] * __uint_as_float(kc.w << 16);
        a += qf[7] * __uint_as_float(kc.w & 0xffff0000u);
        p[s] = a;
    }
#pragma unroll
    for (int s = 0; s < NSLOT; ++s) {
        float v = p[s];
        v += __shfl_xor(v, 1, 64);
        v += __shfl_xor(v, 2, 64);
        v += __shfl_xor(v, 4, 64);
        p[s] = v;
    }
    float mx = p[0];
#pragma unroll
    for (int s = 1; s < NSLOT; ++s) mx = fmaxf(mx, p[s]);
    float den = 0.f;
#pragma unroll
    for (int s = 0; s < NSLOT; ++s) { p[s] = __expf((p[s] - mx) * 0.125f); den += p[s]; }
    float inv = 1.0f / den;
#pragma unroll
    for (int s = 0; s < NSLOT; ++s) p[s] *= inv;
    const ushort* vbase = vb + (((size_t)(b * NHEAD + h)) * NSLOT) * HDIM + d0;
    float cx[8] = {0.f, 0.f, 0.f, 0.f, 0.f, 0.f, 0.f, 0.f};
#pragma unroll
    for (int s = 0; s < NSLOT; ++s) {
        uint4 vc = *(const uint4*)(vbase + s * HDIM);
        float es = p[s];
        cx[0] += es * __uint_as_float(vc.x << 16);
        cx[1] += es * __uint_as_float(vc.x & 0xffff0000u);
        cx[2] += es * __uint_as_float(vc.y << 16);
        cx[3] += es * __uint_as_float(vc.y & 0xffff0000u);
        cx[4] += es * __uint_as_float(vc.z << 16);
        cx[5] += es * __uint_as_float(vc.z & 0xffff0000u);
        cx[6] += es * __uint_as_float(vc.w << 16);
        cx[7] += es * __uint_as_float(vc.w & 0xffff0000u);
    }
    uint4 o;
    o.x = (uint)f2bf(cx[0]) | ((uint)f2bf(cx[1]) << 16);
    o.y = (uint)f2bf(cx[2]) | ((uint)f2bf(cx[3]) << 16);
    o.z = (uint)f2bf(cx[4]) | ((uint)f2bf(cx[5]) << 16);
    o.w = (uint)f2bf(cx[6]) | ((uint)f2bf(cx[7]) << 16);
    *(uint4*)(ctxb + ((size_t)(b * LSEQ + l)) * D + h * HDIM + d0) = o;
}

// ---------------- small-M bf16 MFMA GEMM (M<=128 rows); optional kv-split output --
template <int BM>
__global__ __launch_bounds__(256) void gemm_bt(
    const ushort* __restrict__ A, const ushort* __restrict__ Bw,
    const float* __restrict__ bias, float* __restrict__ C,
    int M, int N, int K, ushort* __restrict__ kvk, ushort* __restrict__ kvv) {
    constexpr int BN = 128, BK = 32;
    constexpr int MF = BM / 32;
    constexpr int APASS = (BM * BK / 8) / 256;
    __shared__ short lds[2][(BM + BN) * BK];
    int tid = threadIdx.x;
    int lane = tid & 63, w = tid >> 6;
    int wr = w >> 1, wc = w & 1;
    int tn = blockIdx.x * BN;
    int tm = blockIdx.y * BM;
    f32x4 acc[MF][4];
    f32x4 zero = {0.f, 0.f, 0.f, 0.f};
#pragma unroll
    for (int m = 0; m < MF; ++m)
#pragma unroll
        for (int n = 0; n < 4; ++n) acc[m][n] = zero;
    int NT = K / BK;

    auto stage = [&](int buf, int t) {
        int kt = t * BK;
#pragma unroll
        for (int p = 0; p < APASS; ++p) {
            int cb = p * 256 + w * 64;
            int c = cb + lane;
            int r = c >> 2;
            int k8 = (c & 3) * 8;
            int gr = tm + r;
            if (gr >= M) gr = M - 1;
            gl_lds16(A + (size_t)gr * K + kt + k8, (void*)&lds[buf][cb * 8]);
        }
#pragma unroll
        for (int p = 0; p < 2; ++p) {
            int cb = p * 256 + w * 64;
            int c = cb + lane;
            int r = c >> 2;
            int k8 = (c & 3) * 8;
            gl_lds16(Bw + (size_t)(tn + r) * K + kt + k8,
                     (void*)&lds[buf][BM * BK + cb * 8]);
        }
    };
    stage(0, 0);
    for (int t = 0; t < NT; ++t) {
        __syncthreads();
        if (t + 1 < NT) stage((t + 1) & 1, t + 1);
        const short* Ab = &lds[t & 1][0];
        const short* Bb = &lds[t & 1][BM * BK];
        int ko = (lane >> 4) * 8;
        int rr = lane & 15;
        bf16x8 af[MF], bfr[4];
#pragma unroll
        for (int m = 0; m < MF; ++m)
            af[m] = *(const bf16x8*)&Ab[(wr * (MF * 16) + m * 16 + rr) * BK + ko];
#pragma unroll
        for (int n = 0; n < 4; ++n)
            bfr[n] = *(const bf16x8*)&Bb[(wc * 64 + n * 16 + rr) * BK + ko];
#pragma unroll
        for (int m = 0; m < MF; ++m)
#pragma unroll
            for (int n = 0; n < 4; ++n)
                acc[m][n] = __builtin_amdgcn_mfma_f32_16x16x32_bf16(af[m], bfr[n],
                                                                    acc[m][n], 0, 0, 0);
    }
#pragma unroll
    for (int m = 0; m < MF; ++m) {
#pragma unroll
        for (int n = 0; n < 4; ++n) {
            int col = tn + wc * 64 + n * 16 + (lane & 15);
            float bsv = bias ? bias[col] : 0.f;
#pragma unroll
            for (int r = 0; r < 4; ++r) {
                int rowi = tm + wr * (MF * 16) + m * 16 + (lane >> 4) * 4 + r;
                if (rowi >= M) continue;
                float v = acc[m][n][r] + bsv;
                if (kvk) {
                    // kv mode: row = b*16+s, col<2048 -> K head h, else V
                    int b = rowi >> 4, s = rowi & 15;
                    int c2 = (col < 2048) ? col : col - 2048;
                    int h = c2 >> 6, d = c2 & 63;
                    size_t dst = (((size_t)(b * NHEAD + h)) * NSLOT + s) * HDIM + d;
                    if (col < 2048) kvk[dst] = f2bf(v);
                    else            kvv[dst] = f2bf(v);
                } else {
                    C[(size_t)rowi * N + col] = v;
                }
            }
        }
    }
}

// ---------------- big GEMM v2: 256x256 tile, BK=32, 4-buf ring, 1 barrier/iter ----
// Stage for tile t+3 is issued RIGHT AFTER the barrier (before compute) so HBM
// latency hides under the 32-MFMA cluster. Per-wave vmcnt before its barrier
// guarantees tile t is fully in LDS after the barrier (same invariant as the
// proven 2-barrier version). Ring safety: writer targets (t+3)&3, readers in
// iters t / t+1 touch t&3 / (t+1)&3 — disjoint; barrier bounds skew to 1 iter.
// K-accumulation order identical to v1 -> bit-identical output.
template <typename OT>
__global__ __launch_bounds__(512, 2) void gemm_big(
    const ushort* __restrict__ A, const ushort* __restrict__ Bw,
    const float* __restrict__ bias, OT* __restrict__ C,
    int M, int N, int K) {
    // paired-row LDS: [128 lds-rows][8 chunks of 16B]; logical (r,c∈0..3):
    // L=r>>1, lc=(r&1)*4+c, slot=lc^(L&7)  (involution applied on global src)
    __shared__ ushort Al[4][128 * 64];   // 4 x 16 KiB
    __shared__ ushort Bl[4][128 * 64];   // 4 x 16 KiB
    int blk = blockIdx.x;
    int bn = blk & 7;                    // same-XCD blocks share B panel (L2)
    int bm = blk >> 3;
    int tid = threadIdx.x;
    int lane = tid & 63, wv = tid >> 6;
    int wm = wv >> 2, wn = wv & 3;       // 2 x 4 wave grid -> 128x64 per wave
    int rr = lane & 15, ko = lane >> 4;  // frag row, k-octet 0..3 (K=32)
    const size_t rowA0 = (size_t)bm * 256;
    const size_t rowB0 = (size_t)bn * 256;

    auto stage = [&](int t) {
        int buf = t & 3;
        int kt = t * 32;
#pragma unroll
        for (int p = 0; p < 2; ++p) {
            int cb = p * 512 + wv * 64;          // wave-uniform chunk base
            int ch = cb + lane;
            int L = ch >> 3, slot = ch & 7;
            int lc = slot ^ (L & 7);
            int r = 2 * L + (lc >> 2);
            int c = lc & 3;
            gl_lds16(A + (rowA0 + r) * K + kt + c * 8,
                     (void*)((char*)&Al[buf][0] + cb * 16));
        }
#pragma unroll
        for (int p = 0; p < 2; ++p) {
            int cb = p * 512 + wv * 64;
            int ch = cb + lane;
            int L = ch >> 3, slot = ch & 7;
            int lc = slot ^ (L & 7);
            int r = 2 * L + (lc >> 2);
            int c = lc & 3;
            gl_lds16(Bw + (rowB0 + r) * K + kt + c * 8,
                     (void*)((char*)&Bl[buf][0] + cb * 16));
        }
    };

    f32x4 acc[8][4];
    f32x4 zero = {0.f, 0.f, 0.f, 0.f};
#pragma unroll
    for (int m = 0; m < 8; ++m)
#pragma unroll
        for (int n = 0; n < 4; ++n) acc[m][n] = zero;

    int NT = K / 32;                     // 64
    stage(0); stage(1); stage(2);        // 12 loads/thread in flight
    for (int t = 0; t < NT; ++t) {
        // wait for tile t's 4 loads; keep t+1/t+2's in flight
        if (t + 3 <= NT)      asm volatile("s_waitcnt vmcnt(8)" ::: "memory");
        else if (t + 2 <= NT) asm volatile("s_waitcnt vmcnt(4)" ::: "memory");
        else                  asm volatile("s_waitcnt vmcnt(0)" ::: "memory");
        asm volatile("s_barrier" ::: "memory");   // all waves' tile-t loads landed
        if (t + 3 < NT) stage(t + 3);             // issue early: hides under MFMA
        const ushort* Ab = &Al[t & 3][0];
        const ushort* Bb = &Bl[t & 3][0];
        bf16x8 bfr[4];
#pragma unroll
        for (int n = 0; n < 4; ++n) {
            int rb = wn * 64 + n * 16 + rr;
            int L = rb >> 1;
            int lc = (rb & 1) * 4 + ko;
            bfr[n] = *(const bf16x8*)((const char*)Bb + L * 128 + ((lc ^ (L & 7)) * 16));
        }
        __builtin_amdgcn_s_setprio(1);
#pragma unroll
        for (int m = 0; m < 8; ++m) {
            int ra = wm * 128 + m * 16 + rr;
            int L = ra >> 1;
            int lc = (ra & 1) * 4 + ko;
            bf16x8 a = *(const bf16x8*)((const char*)Ab + L * 128 + ((lc ^ (L & 7)) * 16));
#pragma unroll
            for (int n = 0; n < 4; ++n)
                acc[m][n] = __builtin_amdgcn_mfma_f32_16x16x32_bf16(a, bfr[n],
                                                                    acc[m][n], 0, 0, 0);
        }
        __builtin_amdgcn_s_setprio(0);
    }
    int crow0 = (int)rowA0 + wm * 128;
    int ccol0 = bn * 256 + wn * 64;
#pragma unroll
    for (int m = 0; m < 8; ++m)
#pragma unroll
        for (int n = 0; n < 4; ++n) {
            int col = ccol0 + n * 16 + rr;
            float bsv = bias ? bias[col] : 0.f;
#pragma unroll
            for (int r4 = 0; r4 < 4; ++r4) {
                int row = crow0 + m * 16 + ko * 4 + r4;
                float v = acc[m][n][r4] + bsv;
                if constexpr (sizeof(OT) == 2) {
                    ((ushort*)C)[(size_t)row * N + col] = f2bf(v);
                } else {
                    ((float*)C)[(size_t)row * N + col] = v;
                }
            }
        }
}

extern "C" void kernel_launch(void* const* d_in, const int* in_sizes, int n_in,
                              void* d_out, int out_size, void* d_ws, size_t ws_size,
                              hipStream_t stream) {
    const float* x_in       = (const float*)d_in[0];
    const float* workspace  = (const float*)d_in[1];
    const float* compete_w  = (const float*)d_in[2];
    const float* compete_b  = (const float*)d_in[3];
    const float* write_w    = (const float*)d_in[4];
    const float* write_b    = (const float*)d_in[5];
    const float* in_proj_w  = (const float*)d_in[6];
    const float* in_proj_b  = (const float*)d_in[7];
    const float* out_proj_w = (const float*)d_in[8];
    const float* out_proj_b = (const float*)d_in[9];
    const float* norm_pre_w  = (const float*)d_in[12];
    const float* norm_post_w = (const float*)d_in[13];
    float* xout = (float*)d_out;

    char* base = (char*)d_ws;
    size_t off = 0;
    auto alloc = [&](size_t bytes) {
        void* p = base + off;
        off += (bytes + 255) & ~(size_t)255;
        return p;
    };
    ushort* xb      = (ushort*)alloc((size_t)BL * D * 2);
    float*  qbuf    = (float*) alloc((size_t)BL * D * 4);     // attn_out (f32)
    ushort* qbb     = (ushort*)alloc((size_t)BL * D * 2);     // q bf16
    ushort* ctxb    = (ushort*)alloc((size_t)BL * D * 2);
    float*  logits  = (float*) alloc((size_t)BATCH * NSLOT * LSEQ * 4);
    ushort* xbar    = (ushort*)alloc((size_t)BATCH * NSLOT * D * 2);
    float*  written = (float*) alloc((size_t)BATCH * NSLOT * D * 4);
    float*  wsbuf   = (float*) alloc((size_t)BATCH * NSLOT * D * 4);
    ushort* wsb     = (ushort*)alloc((size_t)BATCH * NSLOT * D * 2);
    ushort* ipb     = (ushort*)alloc((size_t)3 * D * D * 2);
    ushort* wob     = (ushort*)alloc((size_t)D * D * 2);
    ushort* wwb     = (ushort*)alloc((size_t)D * D * 2);
    ushort* kb16    = (ushort*)alloc((size_t)BATCH * NHEAD * NSLOT * HDIM * 2);
    ushort* vb16    = (ushort*)alloc((size_t)BATCH * NHEAD * NSLOT * HDIM * 2);
    (void)ws_size; (void)in_sizes; (void)n_in; (void)out_size;

    conv_bf16_kernel<<<2048, 256, 0, stream>>>((const float4*)in_proj_w, ipb, 3 * D * D / 4);
    conv_bf16_kernel<<<2048, 256, 0, stream>>>((const float4*)out_proj_w, wob, D * D / 4);
    conv_bf16_kernel<<<2048, 256, 0, stream>>>((const float4*)write_w, wwb, D * D / 4);
    conv_bf16_kernel<<<2048, 256, 0, stream>>>((const float4*)x_in, xb, BL * D / 4);

    for (int it = 0; it < 2; ++it) {
        const float* xs = it ? (const float*)xout : x_in;
        logits_kernel<<<BL / 4, 256, 0, stream>>>(xs, compete_w, compete_b, norm_pre_w,
                                                  logits);
        topk_xbar_kernel<<<BATCH * NSLOT, 256, 0, stream>>>(logits, xs, xbar);
        gemm_bt<64><<<dim3(D / 128, 1), 256, 0, stream>>>(xbar, wwb, write_b, written,
                                                          BATCH * NSLOT, D, D,
                                                          (ushort*)nullptr, (ushort*)nullptr);
        ws_update_kernel<<<BATCH * NSLOT, 256, 0, stream>>>(written, wsbuf, workspace,
                                                            it == 0 ? 1 : 0, norm_post_w,
                                                            wsbuf, wsb);
        gemm_bt<64><<<dim3(2 * D / 128, 1), 256, 0, stream>>>(wsb, ipb + (size_t)D * D,
                                                              in_proj_b + D, (float*)nullptr,
                                                              BATCH * NSLOT, 2 * D, D,
                                                              kb16, vb16);
        gemm_big<ushort><<<(D / 256) * (BL / 256), 512, 0, stream>>>(xb, ipb, in_proj_b,
                                                                     qbb, BL, D, D);
        attn_kernel<<<BL * NHEAD * 8 / 256, 256, 0, stream>>>(qbb, kb16, vb16, ctxb);
        gemm_big<float><<<(D / 256) * (BL / 256), 512, 0, stream>>>(ctxb, wob, out_proj_b,
                                                                    qbuf, BL, D, D);
        resid_rms_kernel<<<BL, 256, 0, stream>>>(xs, qbuf, norm_post_w, xout, xb);
    }
}

// Round 9
// 779.828 us; speedup vs baseline: 1.0819x; 1.0819x over previous
//
#include <hip/hip_runtime.h>
#include <stdint.h>

#define D 2048
#define LSEQ 2048
#define BATCH 4
#define BL (BATCH * LSEQ)   // 8192 rows
#define NSLOT 16
#define NHEAD 32
#define HDIM 64
#define EPSV 1e-6f

typedef __attribute__((ext_vector_type(8))) short bf16x8;
typedef __attribute__((ext_vector_type(4))) float f32x4;

static __device__ __forceinline__ ushort f2bf(float f) {
    uint32_t u = __float_as_uint(f);
    u += 0x7fffu + ((u >> 16) & 1u);   // RNE
    return (ushort)(u >> 16);
}

static __device__ __forceinline__ float wave_sum(float v) {
#pragma unroll
    for (int off = 32; off > 0; off >>= 1) v += __shfl_xor(v, off, 64);
    return v;
}

static __device__ __forceinline__ void gl_lds16(const void* g, void* l) {
    __builtin_amdgcn_global_load_lds(
        (__attribute__((address_space(1))) uint32_t*)(uintptr_t)g,
        (__attribute__((address_space(3))) uint32_t*)(uint32_t)(uintptr_t)l,
        16, 0, 0);
}

// ---------------- weight convert f32 -> bf16 ----------------
__global__ __launch_bounds__(256) void conv_bf16_kernel(const float4* __restrict__ src,
                                                        ushort* __restrict__ dst, int n4) {
    int i = blockIdx.x * 256 + threadIdx.x;
    int stride = gridDim.x * 256;
    for (; i < n4; i += stride) {
        float4 v = src[i];
        uint2 o;
        o.x = (uint)f2bf(v.x) | ((uint)f2bf(v.y) << 16);
        o.y = (uint)f2bf(v.z) | ((uint)f2bf(v.w) << 16);
        *(uint2*)(dst + (size_t)i * 4) = o;
    }
}

// ---------------- logits v4: 4 rows/block, BIT-EXACT to the R4-passing kernel ----
// DO NOT change any arithmetic here: logits bits feed top-k (an order-statistic
// discontinuity); R5 failed from a 1e-7-level summation-order change.
__global__ __launch_bounds__(256) void logits_kernel(
    const float* __restrict__ x, const float* __restrict__ cw,
    const float* __restrict__ cb, const float* __restrict__ wpre,
    float* __restrict__ logits_t) {
    int blk = blockIdx.x;              // 2048 blocks, 4 rows each
    int b = blk >> 9;                  // 512 blocks per batch
    int l0 = (blk & 511) << 2;
    int tid = threadIdx.x;
    int i0 = tid * 8;
    float4 w0 = *(const float4*)(wpre + i0);
    float4 w1 = *(const float4*)(wpre + i0 + 4);
    float wv[8] = {w0.x, w0.y, w0.z, w0.w, w1.x, w1.y, w1.z, w1.w};
    float xw[4][8];
    float ss[4];
#pragma unroll
    for (int r = 0; r < 4; ++r) {
        const float* xr = x + ((size_t)(b * LSEQ + l0 + r)) * D;
        float4 a0 = *(const float4*)(xr + i0);
        float4 a1 = *(const float4*)(xr + i0 + 4);
        float xv[8] = {a0.x, a0.y, a0.z, a0.w, a1.x, a1.y, a1.z, a1.w};
        float s0 = 0.f;
#pragma unroll
        for (int j = 0; j < 8; ++j) { s0 += xv[j] * xv[j]; xw[r][j] = xv[j] * wv[j]; }
        ss[r] = s0;
    }
    float acc[NSLOT][4];
#pragma unroll
    for (int s = 0; s < NSLOT; ++s) {
        const float* cwr = cw + (size_t)s * D + i0;
        float4 c0 = *(const float4*)(cwr);
        float4 c1 = *(const float4*)(cwr + 4);
#pragma unroll
        for (int r = 0; r < 4; ++r)
            acc[s][r] = xw[r][0] * c0.x + xw[r][1] * c0.y + xw[r][2] * c0.z + xw[r][3] * c0.w +
                        xw[r][4] * c1.x + xw[r][5] * c1.y + xw[r][6] * c1.z + xw[r][7] * c1.w;
    }
#pragma unroll
    for (int r = 0; r < 4; ++r) ss[r] = wave_sum(ss[r]);
#pragma unroll
    for (int s = 0; s < NSLOT; ++s)
#pragma unroll
        for (int r = 0; r < 4; ++r) acc[s][r] = wave_sum(acc[s][r]);
    __shared__ float red[4][NSLOT][4];
    __shared__ float redss[4][4];
    int lane = tid & 63, w = tid >> 6;
    if (lane == 0) {
#pragma unroll
        for (int r = 0; r < 4; ++r) redss[w][r] = ss[r];
#pragma unroll
        for (int s = 0; s < NSLOT; ++s)
#pragma unroll
            for (int r = 0; r < 4; ++r) red[w][s][r] = acc[s][r];
    }
    __syncthreads();
    if (tid < 64) {
        int s = tid >> 2, r = tid & 3;
        float tot = red[0][s][r] + red[1][s][r] + red[2][s][r] + red[3][s][r];
        float s2 = redss[0][r] + redss[1][r] + redss[2][r] + redss[3][r];
        float rsq = 1.0f / sqrtf(s2 * (1.0f / (float)D) + EPSV);
        logits_t[((size_t)(b * NSLOT + s)) * LSEQ + l0 + r] = tot * rsq + cb[s];
    }
}

// ---------------- top-4 + softmax + weighted row gather (xbar, bf16) ----------------
__global__ __launch_bounds__(256) void topk_xbar_kernel(
    const float* __restrict__ logits_t, const float* __restrict__ x,
    ushort* __restrict__ xbar_b) {
    int bs = blockIdx.x;
    int b = bs >> 4;
    const float* lr = logits_t + (size_t)bs * LSEQ;
    int tid = threadIdx.x, lane = tid & 63, w = tid >> 6;
    __shared__ float rv[4];
    __shared__ int ri[4];
    __shared__ float selv[4];
    __shared__ int seli[4];
    int i0 = tid * 8;
    float myv[8];
#pragma unroll
    for (int j = 0; j < 8; ++j) myv[j] = lr[i0 + j];
    int chosen[4];
    for (int p = 0; p < 4; ++p) {
        float bv = -3.4e38f;
        int bi = 0x7fffffff;
#pragma unroll
        for (int j = 0; j < 8; ++j) {
            int i = i0 + j;
            bool skip = false;
            for (int q = 0; q < p; ++q) skip = skip || (i == chosen[q]);
            float v = myv[j];
            if (!skip && (v > bv || (v == bv && i < bi))) { bv = v; bi = i; }
        }
#pragma unroll
        for (int off = 1; off < 64; off <<= 1) {
            float ov = __shfl_xor(bv, off, 64);
            int oi = __shfl_xor(bi, off, 64);
            if (ov > bv || (ov == bv && oi < bi)) { bv = ov; bi = oi; }
        }
        if (lane == 0) { rv[w] = bv; ri[w] = bi; }
        __syncthreads();
        if (tid == 0) {
            float fv = rv[0];
            int fi = ri[0];
            for (int q = 1; q < 4; ++q)
                if (rv[q] > fv || (rv[q] == fv && ri[q] < fi)) { fv = rv[q]; fi = ri[q]; }
            selv[p] = fv;
            seli[p] = fi;
        }
        __syncthreads();
        chosen[p] = seli[p];
    }
    float vals[4];
#pragma unroll
    for (int p = 0; p < 4; ++p) vals[p] = selv[p];
    float mx = vals[0];   // first pick is the max
    float e[4], den = 0.f;
#pragma unroll
    for (int p = 0; p < 4; ++p) { e[p] = expf(vals[p] - mx); den += e[p]; }
    float inv = 1.0f / den;
    const float* xr0 = x + ((size_t)b * LSEQ + chosen[0]) * D;
    const float* xr1 = x + ((size_t)b * LSEQ + chosen[1]) * D;
    const float* xr2 = x + ((size_t)b * LSEQ + chosen[2]) * D;
    const float* xr3 = x + ((size_t)b * LSEQ + chosen[3]) * D;
    float s[8];
#pragma unroll
    for (int j = 0; j < 8; ++j) {
        int i = i0 + j;
        s[j] = (e[0] * xr0[i] + e[1] * xr1[i] + e[2] * xr2[i] + e[3] * xr3[i]) * inv;
    }
    uint4 o;
    o.x = (uint)f2bf(s[0]) | ((uint)f2bf(s[1]) << 16);
    o.y = (uint)f2bf(s[2]) | ((uint)f2bf(s[3]) << 16);
    o.z = (uint)f2bf(s[4]) | ((uint)f2bf(s[5]) << 16);
    o.w = (uint)f2bf(s[6]) | ((uint)f2bf(s[7]) << 16);
    *(uint4*)(xbar_b + (size_t)bs * D + i0) = o;
}

// ---------------- ws = rms(ws_prev + written) (+bf16 copy) ----------------
__global__ __launch_bounds__(256) void ws_update_kernel(
    const float* __restrict__ written, const float* __restrict__ ws_prev,
    const float* __restrict__ workspace0, int first,
    const float* __restrict__ wpost, float* __restrict__ ws_out,
    ushort* __restrict__ ws_b) {
    int bs = blockIdx.x;
    int s = bs & (NSLOT - 1);
    int tid = threadIdx.x;
    int i0 = tid * 8;
    const float* prev = first ? (workspace0 + (size_t)s * D) : (ws_prev + (size_t)bs * D);
    const float* wr = written + (size_t)bs * D;
    float4 p0 = *(const float4*)(prev + i0);
    float4 p1 = *(const float4*)(prev + i0 + 4);
    float4 q0 = *(const float4*)(wr + i0);
    float4 q1 = *(const float4*)(wr + i0 + 4);
    float t[8] = {p0.x + q0.x, p0.y + q0.y, p0.z + q0.z, p0.w + q0.w,
                  p1.x + q1.x, p1.y + q1.y, p1.z + q1.z, p1.w + q1.w};
    float ss = 0.f;
#pragma unroll
    for (int j = 0; j < 8; ++j) ss += t[j] * t[j];
    ss = wave_sum(ss);
    __shared__ float sb[4];
    if ((tid & 63) == 0) sb[tid >> 6] = ss;
    __syncthreads();
    ss = sb[0] + sb[1] + sb[2] + sb[3];
    float rsq = 1.0f / sqrtf(ss * (1.0f / (float)D) + EPSV);
    float4 w0 = *(const float4*)(wpost + i0);
    float4 w1 = *(const float4*)(wpost + i0 + 4);
    float wv[8] = {w0.x, w0.y, w0.z, w0.w, w1.x, w1.y, w1.z, w1.w};
    float o[8];
#pragma unroll
    for (int j = 0; j < 8; ++j) o[j] = t[j] * rsq * wv[j];
    float4 r0 = {o[0], o[1], o[2], o[3]};
    float4 r1 = {o[4], o[5], o[6], o[7]};
    *(float4*)(ws_out + (size_t)bs * D + i0) = r0;
    *(float4*)(ws_out + (size_t)bs * D + i0 + 4) = r1;
    uint4 ob;
    ob.x = (uint)f2bf(o[0]) | ((uint)f2bf(o[1]) << 16);
    ob.y = (uint)f2bf(o[2]) | ((uint)f2bf(o[3]) << 16);
    ob.z = (uint)f2bf(o[4]) | ((uint)f2bf(o[5]) << 16);
    ob.w = (uint)f2bf(o[6]) | ((uint)f2bf(o[7]) << 16);
    *(uint4*)(ws_b + (size_t)bs * D + i0) = ob;
}

// ---------------- x = rms(x + attn_out) (+bf16 copy) ----------------
__global__ __launch_bounds__(256) void resid_rms_kernel(
    const float* __restrict__ x_src, const float* __restrict__ ao,
    const float* __restrict__ wpost, float* __restrict__ x_dst,
    ushort* __restrict__ xb) {
    int row = blockIdx.x;
    int tid = threadIdx.x;
    int i0 = tid * 8;
    const float* xr = x_src + (size_t)row * D;
    const float* ar = ao + (size_t)row * D;
    float4 p0 = *(const float4*)(xr + i0);
    float4 p1 = *(const float4*)(xr + i0 + 4);
    float4 q0 = *(const float4*)(ar + i0);
    float4 q1 = *(const float4*)(ar + i0 + 4);
    float t[8] = {p0.x + q0.x, p0.y + q0.y, p0.z + q0.z, p0.w + q0.w,
                  p1.x + q1.x, p1.y + q1.y, p1.z + q1.z, p1.w + q1.w};
    float ss = 0.f;
#pragma unroll
    for (int j = 0; j < 8; ++j) ss += t[j] * t[j];
    ss = wave_sum(ss);
    __shared__ float sb[4];
    if ((tid & 63) == 0) sb[tid >> 6] = ss;
    __syncthreads();
    ss = sb[0] + sb[1] + sb[2] + sb[3];
    float rsq = 1.0f / sqrtf(ss * (1.0f / (float)D) + EPSV);
    float4 w0 = *(const float4*)(wpost + i0);
    float4 w1 = *(const float4*)(wpost + i0 + 4);
    float wv[8] = {w0.x, w0.y, w0.z, w0.w, w1.x, w1.y, w1.z, w1.w};
    float o[8];
#pragma unroll
    for (int j = 0; j < 8; ++j) o[j] = t[j] * rsq * wv[j];
    float4 r0 = {o[0], o[1], o[2], o[3]};
    float4 r1 = {o[4], o[5], o[6], o[7]};
    *(float4*)(x_dst + (size_t)row * D + i0) = r0;
    *(float4*)(x_dst + (size_t)row * D + i0 + 4) = r1;
    uint4 ob;
    ob.x = (uint)f2bf(o[0]) | ((uint)f2bf(o[1]) << 16);
    ob.y = (uint)f2bf(o[2]) | ((uint)f2bf(o[3]) << 16);
    ob.z = (uint)f2bf(o[4]) | ((uint)f2bf(o[5]) << 16);
    ob.w = (uint)f2bf(o[6]) | ((uint)f2bf(o[7]) << 16);
    *(uint4*)(xb + (size_t)row * D + i0) = ob;
}

// ---------------- attention v7: registers only, f32 (bf16-valued) K/V ----------------
// Same structure/order as the passing v6, but K/V are stored as f32 whose values
// are EXACTLY the bf16-rounded values (bits<<16) -> the identical f32 numbers
// enter the identical FMA chain (bit-identical ctx), with ~256 fewer unpack
// VALU ops per thread.
__global__ __launch_bounds__(256) void attn_kernel(
    const ushort* __restrict__ qb, const float* __restrict__ kb,
    const float* __restrict__ vb, ushort* __restrict__ ctxb) {
    int g = blockIdx.x * 256 + threadIdx.x;
    int w = g >> 6;                     // global wave id
    int lane = g & 63;
    int b = w >> 13;                    // 8192 waves per batch
    int h = (w >> 8) & 31;
    int lt = w & 255;
    int l = lt * 8 + (lane >> 3);
    int d0 = (lane & 7) * 8;
    uint4 qv = *(const uint4*)(qb + ((size_t)(b * LSEQ + l)) * D + h * HDIM + d0);
    float qf[8];
    qf[0] = __uint_as_float(qv.x << 16);
    qf[1] = __uint_as_float(qv.x & 0xffff0000u);
    qf[2] = __uint_as_float(qv.y << 16);
    qf[3] = __uint_as_float(qv.y & 0xffff0000u);
    qf[4] = __uint_as_float(qv.z << 16);
    qf[5] = __uint_as_float(qv.z & 0xffff0000u);
    qf[6] = __uint_as_float(qv.w << 16);
    qf[7] = __uint_as_float(qv.w & 0xffff0000u);
    const float* kbase = kb + (((size_t)(b * NHEAD + h)) * NSLOT) * HDIM + d0;
    float p[NSLOT];
#pragma unroll
    for (int s = 0; s < NSLOT; ++s) {
        float4 k0 = *(const float4*)(kbase + s * HDIM);
        float4 k1 = *(const float4*)(kbase + s * HDIM + 4);
        float a;
        a  = qf[0] * k0.x;
        a += qf[1] * k0.y;
        a += qf[2] * k0.z;
        a += qf[3] * k0.w;
        a += qf[4] * k1.x;
        a += qf[5] * k1.y;
        a += qf[6] * k1.z;
        a += qf[7] * k1.w;
        p[s] = a;
    }
#pragma unroll
    for (int s = 0; s < NSLOT; ++s) {
        float v = p[s];
        v += __shfl_xor(v, 1, 64);
        v += __shfl_xor(v, 2, 64);
        v += __shfl_xor(v, 4, 64);
        p[s] = v;
    }
    float mx = p[0];
#pragma unroll
    for (int s = 1; s < NSLOT; ++s) mx = fmaxf(mx, p[s]);
    float den = 0.f;
#pragma unroll
    for (int s = 0; s < NSLOT; ++s) { p[s] = __expf((p[s] - mx) * 0.125f); den += p[s]; }
    float inv = 1.0f / den;
#pragma unroll
    for (int s = 0; s < NSLOT; ++s) p[s] *= inv;
    const float* vbase = vb + (((size_t)(b * NHEAD + h)) * NSLOT) * HDIM + d0;
    float cx[8] = {0.f, 0.f, 0.f, 0.f, 0.f, 0.f, 0.f, 0.f};
#pragma unroll
    for (int s = 0; s < NSLOT; ++s) {
        float4 v0 = *(const float4*)(vbase + s * HDIM);
        float4 v1 = *(const float4*)(vbase + s * HDIM + 4);
        float es = p[s];
        cx[0] += es * v0.x;
        cx[1] += es * v0.y;
        cx[2] += es * v0.z;
        cx[3] += es * v0.w;
        cx[4] += es * v1.x;
        cx[5] += es * v1.y;
        cx[6] += es * v1.z;
        cx[7] += es * v1.w;
    }
    uint4 o;
    o.x = (uint)f2bf(cx[0]) | ((uint)f2bf(cx[1]) << 16);
    o.y = (uint)f2bf(cx[2]) | ((uint)f2bf(cx[3]) << 16);
    o.z = (uint)f2bf(cx[4]) | ((uint)f2bf(cx[5]) << 16);
    o.w = (uint)f2bf(cx[6]) | ((uint)f2bf(cx[7]) << 16);
    *(uint4*)(ctxb + ((size_t)(b * LSEQ + l)) * D + h * HDIM + d0) = o;
}

// ---------------- small-M bf16 MFMA GEMM (M<=128 rows); optional kv-split output --
// kv mode writes f32 values that are exactly the bf16-rounded result (bits<<16).
template <int BM>
__global__ __launch_bounds__(256) void gemm_bt(
    const ushort* __restrict__ A, const ushort* __restrict__ Bw,
    const float* __restrict__ bias, float* __restrict__ C,
    int M, int N, int K, float* __restrict__ kvk, float* __restrict__ kvv) {
    constexpr int BN = 128, BK = 32;
    constexpr int MF = BM / 32;
    constexpr int APASS = (BM * BK / 8) / 256;
    __shared__ short lds[2][(BM + BN) * BK];
    int tid = threadIdx.x;
    int lane = tid & 63, w = tid >> 6;
    int wr = w >> 1, wc = w & 1;
    int tn = blockIdx.x * BN;
    int tm = blockIdx.y * BM;
    f32x4 acc[MF][4];
    f32x4 zero = {0.f, 0.f, 0.f, 0.f};
#pragma unroll
    for (int m = 0; m < MF; ++m)
#pragma unroll
        for (int n = 0; n < 4; ++n) acc[m][n] = zero;
    int NT = K / BK;

    auto stage = [&](int buf, int t) {
        int kt = t * BK;
#pragma unroll
        for (int p = 0; p < APASS; ++p) {
            int cb = p * 256 + w * 64;
            int c = cb + lane;
            int r = c >> 2;
            int k8 = (c & 3) * 8;
            int gr = tm + r;
            if (gr >= M) gr = M - 1;
            gl_lds16(A + (size_t)gr * K + kt + k8, (void*)&lds[buf][cb * 8]);
        }
#pragma unroll
        for (int p = 0; p < 2; ++p) {
            int cb = p * 256 + w * 64;
            int c = cb + lane;
            int r = c >> 2;
            int k8 = (c & 3) * 8;
            gl_lds16(Bw + (size_t)(tn + r) * K + kt + k8,
                     (void*)&lds[buf][BM * BK + cb * 8]);
        }
    };
    stage(0, 0);
    for (int t = 0; t < NT; ++t) {
        __syncthreads();
        if (t + 1 < NT) stage((t + 1) & 1, t + 1);
        const short* Ab = &lds[t & 1][0];
        const short* Bb = &lds[t & 1][BM * BK];
        int ko = (lane >> 4) * 8;
        int rr = lane & 15;
        bf16x8 af[MF], bfr[4];
#pragma unroll
        for (int m = 0; m < MF; ++m)
            af[m] = *(const bf16x8*)&Ab[(wr * (MF * 16) + m * 16 + rr) * BK + ko];
#pragma unroll
        for (int n = 0; n < 4; ++n)
            bfr[n] = *(const bf16x8*)&Bb[(wc * 64 + n * 16 + rr) * BK + ko];
#pragma unroll
        for (int m = 0; m < MF; ++m)
#pragma unroll
            for (int n = 0; n < 4; ++n)
                acc[m][n] = __builtin_amdgcn_mfma_f32_16x16x32_bf16(af[m], bfr[n],
                                                                    acc[m][n], 0, 0, 0);
    }
#pragma unroll
    for (int m = 0; m < MF; ++m) {
#pragma unroll
        for (int n = 0; n < 4; ++n) {
            int col = tn + wc * 64 + n * 16 + (lane & 15);
            float bsv = bias ? bias[col] : 0.f;
#pragma unroll
            for (int r = 0; r < 4; ++r) {
                int rowi = tm + wr * (MF * 16) + m * 16 + (lane >> 4) * 4 + r;
                if (rowi >= M) continue;
                float v = acc[m][n][r] + bsv;
                if (kvk) {
                    // kv mode: row = b*16+s, col<2048 -> K head h, else V
                    int b = rowi >> 4, s = rowi & 15;
                    int c2 = (col < 2048) ? col : col - 2048;
                    int h = c2 >> 6, d = c2 & 63;
                    size_t dst = (((size_t)(b * NHEAD + h)) * NSLOT + s) * HDIM + d;
                    float vbf = __uint_as_float(((uint)f2bf(v)) << 16);
                    if (col < 2048) kvk[dst] = vbf;
                    else            kvv[dst] = vbf;
                } else {
                    C[(size_t)rowi * N + col] = v;
                }
            }
        }
    }
}

// ---------------- big GEMM v1 (proven R3-R7): 256x256, BK=64, counted vmcnt ------
template <typename OT>
__global__ __launch_bounds__(512, 2) void gemm_big(
    const ushort* __restrict__ A, const ushort* __restrict__ Bw,
    const float* __restrict__ bias, OT* __restrict__ C,
    int M, int N, int K) {
    __shared__ ushort Al[2][256 * 64];   // 64 KiB
    __shared__ ushort Bl[2][256 * 64];   // 64 KiB
    int blk = blockIdx.x;
    int bn = blk & 7;                    // same-XCD blocks share B panel (L2)
    int bm = blk >> 3;
    int tid = threadIdx.x;
    int lane = tid & 63, wv = tid >> 6;
    int wm = wv >> 2, wn = wv & 3;       // 2 x 4 wave grid -> 128x64 per wave
    int rr = lane & 15, ko = lane >> 4;  // frag row, k-octet 0..3
    const size_t rowA0 = (size_t)bm * 256;
    const size_t rowB0 = (size_t)bn * 256;

    auto stage = [&](int buf, int t) {
        int kt = t * 64;
#pragma unroll
        for (int p = 0; p < 4; ++p) {
            int cb = p * 512 + wv * 64;          // wave-uniform chunk base
            int ch = cb + lane;
            int r = ch >> 3;
            int cl = (ch & 7) ^ (r & 7);         // pre-swizzled source chunk
            gl_lds16(A + (rowA0 + r) * K + kt + cl * 8,
                     (void*)((char*)&Al[buf][0] + cb * 16));
        }
#pragma unroll
        for (int p = 0; p < 4; ++p) {
            int cb = p * 512 + wv * 64;
            int ch = cb + lane;
            int r = ch >> 3;
            int cl = (ch & 7) ^ (r & 7);
            gl_lds16(Bw + (rowB0 + r) * K + kt + cl * 8,
                     (void*)((char*)&Bl[buf][0] + cb * 16));
        }
    };

    f32x4 acc[8][4];
    f32x4 zero = {0.f, 0.f, 0.f, 0.f};
#pragma unroll
    for (int m = 0; m < 8; ++m)
#pragma unroll
        for (int n = 0; n < 4; ++n) acc[m][n] = zero;

    int NT = K / 64;
    stage(0, 0);
    stage(1, 1);
    for (int t = 0; t < NT; ++t) {
        // wait for THIS tile's 8 loads (t+1's 8 may stay in flight)
        if (t + 2 <= NT) asm volatile("s_waitcnt vmcnt(8)" ::: "memory");
        else             asm volatile("s_waitcnt vmcnt(0)" ::: "memory");
        asm volatile("s_barrier" ::: "memory");   // all waves' tile-t loads landed
        const ushort* Ab = &Al[t & 1][0];
        const ushort* Bb = &Bl[t & 1][0];
        bf16x8 bfr[4][2];
#pragma unroll
        for (int n = 0; n < 4; ++n)
#pragma unroll
            for (int ks = 0; ks < 2; ++ks) {
                int r = wn * 64 + n * 16 + rr;
                int cl = ks * 4 + ko;
                bfr[n][ks] = *(const bf16x8*)((const char*)Bb + r * 128 +
                                              ((cl ^ (r & 7)) * 16));
            }
        __builtin_amdgcn_s_setprio(1);
#pragma unroll
        for (int m = 0; m < 8; ++m) {
            int r = wm * 128 + m * 16 + rr;
            bf16x8 a0 = *(const bf16x8*)((const char*)Ab + r * 128 +
                                         (((0 + ko) ^ (r & 7)) * 16));
            bf16x8 a1 = *(const bf16x8*)((const char*)Ab + r * 128 +
                                         (((4 + ko) ^ (r & 7)) * 16));
#pragma unroll
            for (int n = 0; n < 4; ++n) {
                acc[m][n] = __builtin_amdgcn_mfma_f32_16x16x32_bf16(a0, bfr[n][0],
                                                                    acc[m][n], 0, 0, 0);
                acc[m][n] = __builtin_amdgcn_mfma_f32_16x16x32_bf16(a1, bfr[n][1],
                                                                    acc[m][n], 0, 0, 0);
            }
        }
        __builtin_amdgcn_s_setprio(0);
        asm volatile("s_barrier" ::: "memory");   // all waves done reading buf[t&1]
        if (t + 2 < NT) stage(t & 1, t + 2);      // overwrite just-consumed buffer
    }
    int crow0 = (int)rowA0 + wm * 128;
    int ccol0 = bn * 256 + wn * 64;
#pragma unroll
    for (int m = 0; m < 8; ++m)
#pragma unroll
        for (int n = 0; n < 4; ++n) {
            int col = ccol0 + n * 16 + rr;
            float bsv = bias ? bias[col] : 0.f;
#pragma unroll
            for (int r4 = 0; r4 < 4; ++r4) {
                int row = crow0 + m * 16 + ko * 4 + r4;
                float v = acc[m][n][r4] + bsv;
                if constexpr (sizeof(OT) == 2) {
                    ((ushort*)C)[(size_t)row * N + col] = f2bf(v);
                } else {
                    ((float*)C)[(size_t)row * N + col] = v;
                }
            }
        }
}

extern "C" void kernel_launch(void* const* d_in, const int* in_sizes, int n_in,
                              void* d_out, int out_size, void* d_ws, size_t ws_size,
                              hipStream_t stream) {
    const float* x_in       = (const float*)d_in[0];
    const float* workspace  = (const float*)d_in[1];
    const float* compete_w  = (const float*)d_in[2];
    const float* compete_b  = (const float*)d_in[3];
    const float* write_w    = (const float*)d_in[4];
    const float* write_b    = (const float*)d_in[5];
    const float* in_proj_w  = (const float*)d_in[6];
    const float* in_proj_b  = (const float*)d_in[7];
    const float* out_proj_w = (const float*)d_in[8];
    const float* out_proj_b = (const float*)d_in[9];
    const float* norm_pre_w  = (const float*)d_in[12];
    const float* norm_post_w = (const float*)d_in[13];
    float* xout = (float*)d_out;

    char* base = (char*)d_ws;
    size_t off = 0;
    auto alloc = [&](size_t bytes) {
        void* p = base + off;
        off += (bytes + 255) & ~(size_t)255;
        return p;
    };
    ushort* xb      = (ushort*)alloc((size_t)BL * D * 2);
    float*  qbuf    = (float*) alloc((size_t)BL * D * 4);     // attn_out (f32)
    ushort* qbb     = (ushort*)alloc((size_t)BL * D * 2);     // q bf16
    ushort* ctxb    = (ushort*)alloc((size_t)BL * D * 2);
    float*  logits  = (float*) alloc((size_t)BATCH * NSLOT * LSEQ * 4);
    ushort* xbar    = (ushort*)alloc((size_t)BATCH * NSLOT * D * 2);
    float*  written = (float*) alloc((size_t)BATCH * NSLOT * D * 4);
    float*  wsbuf   = (float*) alloc((size_t)BATCH * NSLOT * D * 4);
    ushort* wsb     = (ushort*)alloc((size_t)BATCH * NSLOT * D * 2);
    ushort* ipb     = (ushort*)alloc((size_t)3 * D * D * 2);
    ushort* wob     = (ushort*)alloc((size_t)D * D * 2);
    ushort* wwb     = (ushort*)alloc((size_t)D * D * 2);
    float*  kb32    = (float*) alloc((size_t)BATCH * NHEAD * NSLOT * HDIM * 4);
    float*  vb32    = (float*) alloc((size_t)BATCH * NHEAD * NSLOT * HDIM * 4);
    (void)ws_size; (void)in_sizes; (void)n_in; (void)out_size;

    conv_bf16_kernel<<<2048, 256, 0, stream>>>((const float4*)in_proj_w, ipb, 3 * D * D / 4);
    conv_bf16_kernel<<<2048, 256, 0, stream>>>((const float4*)out_proj_w, wob, D * D / 4);
    conv_bf16_kernel<<<2048, 256, 0, stream>>>((const float4*)write_w, wwb, D * D / 4);
    conv_bf16_kernel<<<2048, 256, 0, stream>>>((const float4*)x_in, xb, BL * D / 4);

    for (int it = 0; it < 2; ++it) {
        const float* xs = it ? (const float*)xout : x_in;
        logits_kernel<<<BL / 4, 256, 0, stream>>>(xs, compete_w, compete_b, norm_pre_w,
                                                  logits);
        topk_xbar_kernel<<<BATCH * NSLOT, 256, 0, stream>>>(logits, xs, xbar);
        gemm_bt<64><<<dim3(D / 128, 1), 256, 0, stream>>>(xbar, wwb, write_b, written,
                                                          BATCH * NSLOT, D, D,
                                                          (float*)nullptr, (float*)nullptr);
        ws_update_kernel<<<BATCH * NSLOT, 256, 0, stream>>>(written, wsbuf, workspace,
                                                            it == 0 ? 1 : 0, norm_post_w,
                                                            wsbuf, wsb);
        gemm_bt<64><<<dim3(2 * D / 128, 1), 256, 0, stream>>>(wsb, ipb + (size_t)D * D,
                                                              in_proj_b + D, (float*)nullptr,
                                                              BATCH * NSLOT, 2 * D, D,
                                                              kb32, vb32);
        gemm_big<ushort><<<(D / 256) * (BL / 256), 512, 0, stream>>>(xb, ipb, in_proj_b,
                                                                     qbb, BL, D, D);
        attn_kernel<<<BL * NHEAD * 8 / 256, 256, 0, stream>>>(qbb, kb32, vb32, ctxb);
        gemm_big<float><<<(D / 256) * (BL / 256), 512, 0, stream>>>(ctxb, wob, out_proj_b,
                                                                    qbuf, BL, D, D);
        resid_rms_kernel<<<BL, 256, 0, stream>>>(xs, qbuf, norm_post_w, xout, xb);
    }
}

// Round 11
// 776.563 us; speedup vs baseline: 1.0864x; 1.0042x over previous
//
#include <hip/hip_runtime.h>
#include <stdint.h>

#define D 2048
#define LSEQ 2048
#define BATCH 4
#define BL (BATCH * LSEQ)   // 8192 rows
#define NSLOT 16
#define NHEAD 32
#define HDIM 64
#define EPSV 1e-6f

typedef __attribute__((ext_vector_type(8))) short bf16x8;
typedef __attribute__((ext_vector_type(4))) float f32x4;

static __device__ __forceinline__ ushort f2bf(float f) {
    uint32_t u = __float_as_uint(f);
    u += 0x7fffu + ((u >> 16) & 1u);   // RNE
    return (ushort)(u >> 16);
}

static __device__ __forceinline__ float wave_sum(float v) {
#pragma unroll
    for (int off = 32; off > 0; off >>= 1) v += __shfl_xor(v, off, 64);
    return v;
}

static __device__ __forceinline__ void gl_lds16(const void* g, void* l) {
    __builtin_amdgcn_global_load_lds(
        (__attribute__((address_space(1))) uint32_t*)(uintptr_t)g,
        (__attribute__((address_space(3))) uint32_t*)(uint32_t)(uintptr_t)l,
        16, 0, 0);
}

// ---------------- weight convert f32 -> bf16 ----------------
__global__ __launch_bounds__(256) void conv_bf16_kernel(const float4* __restrict__ src,
                                                        ushort* __restrict__ dst, int n4) {
    int i = blockIdx.x * 256 + threadIdx.x;
    int stride = gridDim.x * 256;
    for (; i < n4; i += stride) {
        float4 v = src[i];
        uint2 o;
        o.x = (uint)f2bf(v.x) | ((uint)f2bf(v.y) << 16);
        o.y = (uint)f2bf(v.z) | ((uint)f2bf(v.w) << 16);
        *(uint2*)(dst + (size_t)i * 4) = o;
    }
}

// ---------------- logits v4: 4 rows/block, BIT-EXACT to the R4-passing kernel ----
// DO NOT change any arithmetic here: logits bits feed top-k (an order-statistic
// discontinuity); R5 failed from a 1e-7-level summation-order change.
__global__ __launch_bounds__(256) void logits_kernel(
    const float* __restrict__ x, const float* __restrict__ cw,
    const float* __restrict__ cb, const float* __restrict__ wpre,
    float* __restrict__ logits_t) {
    int blk = blockIdx.x;              // 2048 blocks, 4 rows each
    int b = blk >> 9;                  // 512 blocks per batch
    int l0 = (blk & 511) << 2;
    int tid = threadIdx.x;
    int i0 = tid * 8;
    float4 w0 = *(const float4*)(wpre + i0);
    float4 w1 = *(const float4*)(wpre + i0 + 4);
    float wv[8] = {w0.x, w0.y, w0.z, w0.w, w1.x, w1.y, w1.z, w1.w};
    float xw[4][8];
    float ss[4];
#pragma unroll
    for (int r = 0; r < 4; ++r) {
        const float* xr = x + ((size_t)(b * LSEQ + l0 + r)) * D;
        float4 a0 = *(const float4*)(xr + i0);
        float4 a1 = *(const float4*)(xr + i0 + 4);
        float xv[8] = {a0.x, a0.y, a0.z, a0.w, a1.x, a1.y, a1.z, a1.w};
        float s0 = 0.f;
#pragma unroll
        for (int j = 0; j < 8; ++j) { s0 += xv[j] * xv[j]; xw[r][j] = xv[j] * wv[j]; }
        ss[r] = s0;
    }
    float acc[NSLOT][4];
#pragma unroll
    for (int s = 0; s < NSLOT; ++s) {
        const float* cwr = cw + (size_t)s * D + i0;
        float4 c0 = *(const float4*)(cwr);
        float4 c1 = *(const float4*)(cwr + 4);
#pragma unroll
        for (int r = 0; r < 4; ++r)
            acc[s][r] = xw[r][0] * c0.x + xw[r][1] * c0.y + xw[r][2] * c0.z + xw[r][3] * c0.w +
                        xw[r][4] * c1.x + xw[r][5] * c1.y + xw[r][6] * c1.z + xw[r][7] * c1.w;
    }
#pragma unroll
    for (int r = 0; r < 4; ++r) ss[r] = wave_sum(ss[r]);
#pragma unroll
    for (int s = 0; s < NSLOT; ++s)
#pragma unroll
        for (int r = 0; r < 4; ++r) acc[s][r] = wave_sum(acc[s][r]);
    __shared__ float red[4][NSLOT][4];
    __shared__ float redss[4][4];
    int lane = tid & 63, w = tid >> 6;
    if (lane == 0) {
#pragma unroll
        for (int r = 0; r < 4; ++r) redss[w][r] = ss[r];
#pragma unroll
        for (int s = 0; s < NSLOT; ++s)
#pragma unroll
            for (int r = 0; r < 4; ++r) red[w][s][r] = acc[s][r];
    }
    __syncthreads();
    if (tid < 64) {
        int s = tid >> 2, r = tid & 3;
        float tot = red[0][s][r] + red[1][s][r] + red[2][s][r] + red[3][s][r];
        float s2 = redss[0][r] + redss[1][r] + redss[2][r] + redss[3][r];
        float rsq = 1.0f / sqrtf(s2 * (1.0f / (float)D) + EPSV);
        logits_t[((size_t)(b * NSLOT + s)) * LSEQ + l0 + r] = tot * rsq + cb[s];
    }
}

// ---------------- top-4 + softmax + weighted row gather (xbar, bf16) ----------------
__global__ __launch_bounds__(256) void topk_xbar_kernel(
    const float* __restrict__ logits_t, const float* __restrict__ x,
    ushort* __restrict__ xbar_b) {
    int bs = blockIdx.x;
    int b = bs >> 4;
    const float* lr = logits_t + (size_t)bs * LSEQ;
    int tid = threadIdx.x, lane = tid & 63, w = tid >> 6;
    __shared__ float rv[4];
    __shared__ int ri[4];
    __shared__ float selv[4];
    __shared__ int seli[4];
    int i0 = tid * 8;
    float myv[8];
#pragma unroll
    for (int j = 0; j < 8; ++j) myv[j] = lr[i0 + j];
    int chosen[4];
    for (int p = 0; p < 4; ++p) {
        float bv = -3.4e38f;
        int bi = 0x7fffffff;
#pragma unroll
        for (int j = 0; j < 8; ++j) {
            int i = i0 + j;
            bool skip = false;
            for (int q = 0; q < p; ++q) skip = skip || (i == chosen[q]);
            float v = myv[j];
            if (!skip && (v > bv || (v == bv && i < bi))) { bv = v; bi = i; }
        }
#pragma unroll
        for (int off = 1; off < 64; off <<= 1) {
            float ov = __shfl_xor(bv, off, 64);
            int oi = __shfl_xor(bi, off, 64);
            if (ov > bv || (ov == bv && oi < bi)) { bv = ov; bi = oi; }
        }
        if (lane == 0) { rv[w] = bv; ri[w] = bi; }
        __syncthreads();
        if (tid == 0) {
            float fv = rv[0];
            int fi = ri[0];
            for (int q = 1; q < 4; ++q)
                if (rv[q] > fv || (rv[q] == fv && ri[q] < fi)) { fv = rv[q]; fi = ri[q]; }
            selv[p] = fv;
            seli[p] = fi;
        }
        __syncthreads();
        chosen[p] = seli[p];
    }
    float vals[4];
#pragma unroll
    for (int p = 0; p < 4; ++p) vals[p] = selv[p];
    float mx = vals[0];   // first pick is the max
    float e[4], den = 0.f;
#pragma unroll
    for (int p = 0; p < 4; ++p) { e[p] = expf(vals[p] - mx); den += e[p]; }
    float inv = 1.0f / den;
    const float* xr0 = x + ((size_t)b * LSEQ + chosen[0]) * D;
    const float* xr1 = x + ((size_t)b * LSEQ + chosen[1]) * D;
    const float* xr2 = x + ((size_t)b * LSEQ + chosen[2]) * D;
    const float* xr3 = x + ((size_t)b * LSEQ + chosen[3]) * D;
    float s[8];
#pragma unroll
    for (int j = 0; j < 8; ++j) {
        int i = i0 + j;
        s[j] = (e[0] * xr0[i] + e[1] * xr1[i] + e[2] * xr2[i] + e[3] * xr3[i]) * inv;
    }
    uint4 o;
    o.x = (uint)f2bf(s[0]) | ((uint)f2bf(s[1]) << 16);
    o.y = (uint)f2bf(s[2]) | ((uint)f2bf(s[3]) << 16);
    o.z = (uint)f2bf(s[4]) | ((uint)f2bf(s[5]) << 16);
    o.w = (uint)f2bf(s[6]) | ((uint)f2bf(s[7]) << 16);
    *(uint4*)(xbar_b + (size_t)bs * D + i0) = o;
}

// ---------------- ws = rms(ws_prev + written) (+bf16 copy) ----------------
__global__ __launch_bounds__(256) void ws_update_kernel(
    const float* __restrict__ written, const float* __restrict__ ws_prev,
    const float* __restrict__ workspace0, int first,
    const float* __restrict__ wpost, float* __restrict__ ws_out,
    ushort* __restrict__ ws_b) {
    int bs = blockIdx.x;
    int s = bs & (NSLOT - 1);
    int tid = threadIdx.x;
    int i0 = tid * 8;
    const float* prev = first ? (workspace0 + (size_t)s * D) : (ws_prev + (size_t)bs * D);
    const float* wr = written + (size_t)bs * D;
    float4 p0 = *(const float4*)(prev + i0);
    float4 p1 = *(const float4*)(prev + i0 + 4);
    float4 q0 = *(const float4*)(wr + i0);
    float4 q1 = *(const float4*)(wr + i0 + 4);
    float t[8] = {p0.x + q0.x, p0.y + q0.y, p0.z + q0.z, p0.w + q0.w,
                  p1.x + q1.x, p1.y + q1.y, p1.z + q1.z, p1.w + q1.w};
    float ss = 0.f;
#pragma unroll
    for (int j = 0; j < 8; ++j) ss += t[j] * t[j];
    ss = wave_sum(ss);
    __shared__ float sb[4];
    if ((tid & 63) == 0) sb[tid >> 6] = ss;
    __syncthreads();
    ss = sb[0] + sb[1] + sb[2] + sb[3];
    float rsq = 1.0f / sqrtf(ss * (1.0f / (float)D) + EPSV);
    float4 w0 = *(const float4*)(wpost + i0);
    float4 w1 = *(const float4*)(wpost + i0 + 4);
    float wv[8] = {w0.x, w0.y, w0.z, w0.w, w1.x, w1.y, w1.z, w1.w};
    float o[8];
#pragma unroll
    for (int j = 0; j < 8; ++j) o[j] = t[j] * rsq * wv[j];
    float4 r0 = {o[0], o[1], o[2], o[3]};
    float4 r1 = {o[4], o[5], o[6], o[7]};
    *(float4*)(ws_out + (size_t)bs * D + i0) = r0;
    *(float4*)(ws_out + (size_t)bs * D + i0 + 4) = r1;
    uint4 ob;
    ob.x = (uint)f2bf(o[0]) | ((uint)f2bf(o[1]) << 16);
    ob.y = (uint)f2bf(o[2]) | ((uint)f2bf(o[3]) << 16);
    ob.z = (uint)f2bf(o[4]) | ((uint)f2bf(o[5]) << 16);
    ob.w = (uint)f2bf(o[6]) | ((uint)f2bf(o[7]) << 16);
    *(uint4*)(ws_b + (size_t)bs * D + i0) = ob;
}

// ---------------- x = rms(x + attn_out) (+bf16 copy) ----------------
__global__ __launch_bounds__(256) void resid_rms_kernel(
    const float* __restrict__ x_src, const float* __restrict__ ao,
    const float* __restrict__ wpost, float* __restrict__ x_dst,
    ushort* __restrict__ xb) {
    int row = blockIdx.x;
    int tid = threadIdx.x;
    int i0 = tid * 8;
    const float* xr = x_src + (size_t)row * D;
    const float* ar = ao + (size_t)row * D;
    float4 p0 = *(const float4*)(xr + i0);
    float4 p1 = *(const float4*)(xr + i0 + 4);
    float4 q0 = *(const float4*)(ar + i0);
    float4 q1 = *(const float4*)(ar + i0 + 4);
    float t[8] = {p0.x + q0.x, p0.y + q0.y, p0.z + q0.z, p0.w + q0.w,
                  p1.x + q1.x, p1.y + q1.y, p1.z + q1.z, p1.w + q1.w};
    float ss = 0.f;
#pragma unroll
    for (int j = 0; j < 8; ++j) ss += t[j] * t[j];
    ss = wave_sum(ss);
    __shared__ float sb[4];
    if ((tid & 63) == 0) sb[tid >> 6] = ss;
    __syncthreads();
    ss = sb[0] + sb[1] + sb[2] + sb[3];
    float rsq = 1.0f / sqrtf(ss * (1.0f / (float)D) + EPSV);
    float4 w0 = *(const float4*)(wpost + i0);
    float4 w1 = *(const float4*)(wpost + i0 + 4);
    float wv[8] = {w0.x, w0.y, w0.z, w0.w, w1.x, w1.y, w1.z, w1.w};
    float o[8];
#pragma unroll
    for (int j = 0; j < 8; ++j) o[j] = t[j] * rsq * wv[j];
    float4 r0 = {o[0], o[1], o[2], o[3]};
    float4 r1 = {o[4], o[5], o[6], o[7]};
    *(float4*)(x_dst + (size_t)row * D + i0) = r0;
    *(float4*)(x_dst + (size_t)row * D + i0 + 4) = r1;
    uint4 ob;
    ob.x = (uint)f2bf(o[0]) | ((uint)f2bf(o[1]) << 16);
    ob.y = (uint)f2bf(o[2]) | ((uint)f2bf(o[3]) << 16);
    ob.z = (uint)f2bf(o[4]) | ((uint)f2bf(o[5]) << 16);
    ob.w = (uint)f2bf(o[6]) | ((uint)f2bf(o[7]) << 16);
    *(uint4*)(xb + (size_t)row * D + i0) = ob;
}

// ---------------- attention v7: registers only, f32 (bf16-valued) K/V ----------------
__global__ __launch_bounds__(256) void attn_kernel(
    const ushort* __restrict__ qb, const float* __restrict__ kb,
    const float* __restrict__ vb, ushort* __restrict__ ctxb) {
    int g = blockIdx.x * 256 + threadIdx.x;
    int w = g >> 6;                     // global wave id
    int lane = g & 63;
    int b = w >> 13;                    // 8192 waves per batch
    int h = (w >> 8) & 31;
    int lt = w & 255;
    int l = lt * 8 + (lane >> 3);
    int d0 = (lane & 7) * 8;
    uint4 qv = *(const uint4*)(qb + ((size_t)(b * LSEQ + l)) * D + h * HDIM + d0);
    float qf[8];
    qf[0] = __uint_as_float(qv.x << 16);
    qf[1] = __uint_as_float(qv.x & 0xffff0000u);
    qf[2] = __uint_as_float(qv.y << 16);
    qf[3] = __uint_as_float(qv.y & 0xffff0000u);
    qf[4] = __uint_as_float(qv.z << 16);
    qf[5] = __uint_as_float(qv.z & 0xffff0000u);
    qf[6] = __uint_as_float(qv.w << 16);
    qf[7] = __uint_as_float(qv.w & 0xffff0000u);
    const float* kbase = kb + (((size_t)(b * NHEAD + h)) * NSLOT) * HDIM + d0;
    float p[NSLOT];
#pragma unroll
    for (int s = 0; s < NSLOT; ++s) {
        float4 k0 = *(const float4*)(kbase + s * HDIM);
        float4 k1 = *(const float4*)(kbase + s * HDIM + 4);
        float a;
        a  = qf[0] * k0.x;
        a += qf[1] * k0.y;
        a += qf[2] * k0.z;
        a += qf[3] * k0.w;
        a += qf[4] * k1.x;
        a += qf[5] * k1.y;
        a += qf[6] * k1.z;
        a += qf[7] * k1.w;
        p[s] = a;
    }
#pragma unroll
    for (int s = 0; s < NSLOT; ++s) {
        float v = p[s];
        v += __shfl_xor(v, 1, 64);
        v += __shfl_xor(v, 2, 64);
        v += __shfl_xor(v, 4, 64);
        p[s] = v;
    }
    float mx = p[0];
#pragma unroll
    for (int s = 1; s < NSLOT; ++s) mx = fmaxf(mx, p[s]);
    float den = 0.f;
#pragma unroll
    for (int s = 0; s < NSLOT; ++s) { p[s] = __expf((p[s] - mx) * 0.125f); den += p[s]; }
    float inv = 1.0f / den;
#pragma unroll
    for (int s = 0; s < NSLOT; ++s) p[s] *= inv;
    const float* vbase = vb + (((size_t)(b * NHEAD + h)) * NSLOT) * HDIM + d0;
    float cx[8] = {0.f, 0.f, 0.f, 0.f, 0.f, 0.f, 0.f, 0.f};
#pragma unroll
    for (int s = 0; s < NSLOT; ++s) {
        float4 v0 = *(const float4*)(vbase + s * HDIM);
        float4 v1 = *(const float4*)(vbase + s * HDIM + 4);
        float es = p[s];
        cx[0] += es * v0.x;
        cx[1] += es * v0.y;
        cx[2] += es * v0.z;
        cx[3] += es * v0.w;
        cx[4] += es * v1.x;
        cx[5] += es * v1.y;
        cx[6] += es * v1.z;
        cx[7] += es * v1.w;
    }
    uint4 o;
    o.x = (uint)f2bf(cx[0]) | ((uint)f2bf(cx[1]) << 16);
    o.y = (uint)f2bf(cx[2]) | ((uint)f2bf(cx[3]) << 16);
    o.z = (uint)f2bf(cx[4]) | ((uint)f2bf(cx[5]) << 16);
    o.w = (uint)f2bf(cx[6]) | ((uint)f2bf(cx[7]) << 16);
    *(uint4*)(ctxb + ((size_t)(b * LSEQ + l)) * D + h * HDIM + d0) = o;
}

// ---------------- small-M bf16 MFMA GEMM (M<=128 rows); optional kv-split output --
template <int BM>
__global__ __launch_bounds__(256) void gemm_bt(
    const ushort* __restrict__ A, const ushort* __restrict__ Bw,
    const float* __restrict__ bias, float* __restrict__ C,
    int M, int N, int K, float* __restrict__ kvk, float* __restrict__ kvv) {
    constexpr int BN = 128, BK = 32;
    constexpr int MF = BM / 32;
    constexpr int APASS = (BM * BK / 8) / 256;
    __shared__ short lds[2][(BM + BN) * BK];
    int tid = threadIdx.x;
    int lane = tid & 63, w = tid >> 6;
    int wr = w >> 1, wc = w & 1;
    int tn = blockIdx.x * BN;
    int tm = blockIdx.y * BM;
    f32x4 acc[MF][4];
    f32x4 zero = {0.f, 0.f, 0.f, 0.f};
#pragma unroll
    for (int m = 0; m < MF; ++m)
#pragma unroll
        for (int n = 0; n < 4; ++n) acc[m][n] = zero;
    int NT = K / BK;

    auto stage = [&](int buf, int t) {
        int kt = t * BK;
#pragma unroll
        for (int p = 0; p < APASS; ++p) {
            int cb = p * 256 + w * 64;
            int c = cb + lane;
            int r = c >> 2;
            int k8 = (c & 3) * 8;
            int gr = tm + r;
            if (gr >= M) gr = M - 1;
            gl_lds16(A + (size_t)gr * K + kt + k8, (void*)&lds[buf][cb * 8]);
        }
#pragma unroll
        for (int p = 0; p < 2; ++p) {
            int cb = p * 256 + w * 64;
            int c = cb + lane;
            int r = c >> 2;
            int k8 = (c & 3) * 8;
            gl_lds16(Bw + (size_t)(tn + r) * K + kt + k8,
                     (void*)&lds[buf][BM * BK + cb * 8]);
        }
    };
    stage(0, 0);
    for (int t = 0; t < NT; ++t) {
        __syncthreads();
        if (t + 1 < NT) stage((t + 1) & 1, t + 1);
        const short* Ab = &lds[t & 1][0];
        const short* Bb = &lds[t & 1][BM * BK];
        int ko = (lane >> 4) * 8;
        int rr = lane & 15;
        bf16x8 af[MF], bfr[4];
#pragma unroll
        for (int m = 0; m < MF; ++m)
            af[m] = *(const bf16x8*)&Ab[(wr * (MF * 16) + m * 16 + rr) * BK + ko];
#pragma unroll
        for (int n = 0; n < 4; ++n)
            bfr[n] = *(const bf16x8*)&Bb[(wc * 64 + n * 16 + rr) * BK + ko];
#pragma unroll
        for (int m = 0; m < MF; ++m)
#pragma unroll
            for (int n = 0; n < 4; ++n)
                acc[m][n] = __builtin_amdgcn_mfma_f32_16x16x32_bf16(af[m], bfr[n],
                                                                    acc[m][n], 0, 0, 0);
    }
#pragma unroll
    for (int m = 0; m < MF; ++m) {
#pragma unroll
        for (int n = 0; n < 4; ++n) {
            int col = tn + wc * 64 + n * 16 + (lane & 15);
            float bsv = bias ? bias[col] : 0.f;
#pragma unroll
            for (int r = 0; r < 4; ++r) {
                int rowi = tm + wr * (MF * 16) + m * 16 + (lane >> 4) * 4 + r;
                if (rowi >= M) continue;
                float v = acc[m][n][r] + bsv;
                if (kvk) {
                    // kv mode: row = b*16+s, col<2048 -> K head h, else V
                    int b = rowi >> 4, s = rowi & 15;
                    int c2 = (col < 2048) ? col : col - 2048;
                    int h = c2 >> 6, d = c2 & 63;
                    size_t dst = (((size_t)(b * NHEAD + h)) * NSLOT + s) * HDIM + d;
                    float vbf = __uint_as_float(((uint)f2bf(v)) << 16);
                    if (col < 2048) kvk[dst] = vbf;
                    else            kvv[dst] = vbf;
                } else {
                    C[(size_t)rowi * N + col] = v;
                }
            }
        }
    }
}

// ---------------- big GEMM v3b: 256x256, BK=64, 8-phase (race-fixed) -------------
// RACE FIX vs v3: at q==0 the fragment ds_reads now come AFTER the phase barrier.
// A wave's vmcnt only proves ITS OWN global_load_lds writes landed; the half-tile
// is written by all 8 waves, so reads of freshly confirmed tiles are only safe
// after the barrier that follows every wave's vmcnt. q>=1 reads target data
// confirmed by q==0's barrier and may stay before their phase barrier.
// vmcnt counting, stage schedule, and per-accumulator MFMA order unchanged ->
// bit-identical output to the passing R9 kernel.
template <typename OT>
__global__ __launch_bounds__(512, 2) void gemm_big(
    const ushort* __restrict__ A, const ushort* __restrict__ Bw,
    const float* __restrict__ bias, OT* __restrict__ C,
    int M, int N, int K) {
    __shared__ ushort Al[2][2][128 * 64];   // [dbuf][half] 16 KiB each
    __shared__ ushort Bl[2][2][128 * 64];
    int blk = blockIdx.x;
    int bn = blk & 7;                    // same-XCD blocks share B panel (L2)
    int bm = blk >> 3;
    int tid = threadIdx.x;
    int lane = tid & 63, wv = tid >> 6;
    int wm = wv >> 2, wn = wv & 3;       // 2 x 4 wave grid -> 128x64 per wave
    int rr = lane & 15, ko = lane >> 4;
    const size_t rowA0 = (size_t)bm * 256;
    const size_t rowB0 = (size_t)bn * 256;

    auto stageA = [&](int h, int t) {
        int kt = t * 64;
        ushort* dst = &Al[t & 1][h][0];
#pragma unroll
        for (int p = 0; p < 2; ++p) {
            int cb = p * 512 + wv * 64;          // wave-uniform chunk base
            int ch = cb + lane;
            int Lr = ch >> 3;
            int cl = (ch & 7) ^ (Lr & 7);        // pre-swizzled source chunk
            gl_lds16(A + (rowA0 + h * 128 + Lr) * K + kt + cl * 8,
                     (void*)((char*)dst + cb * 16));
        }
    };
    auto stageB = [&](int h, int t) {
        int kt = t * 64;
        ushort* dst = &Bl[t & 1][h][0];
#pragma unroll
        for (int p = 0; p < 2; ++p) {
            int cb = p * 512 + wv * 64;
            int ch = cb + lane;
            int Lr = ch >> 3;
            int cl = (ch & 7) ^ (Lr & 7);
            gl_lds16(Bw + (rowB0 + h * 128 + Lr) * K + kt + cl * 8,
                     (void*)((char*)dst + cb * 16));
        }
    };

    f32x4 acc[8][4];
    f32x4 zero = {0.f, 0.f, 0.f, 0.f};
#pragma unroll
    for (int m = 0; m < 8; ++m)
#pragma unroll
        for (int n = 0; n < 4; ++n) acc[m][n] = zero;

    int NT = K / 64;     // 32 (even, >=4)
    int NI = NT / 2;
    // prologue: tile0 full, tile1 B-halves (12 loads/thread in flight)
    stageB(0, 0); stageB(1, 0); stageA(0, 0); stageA(1, 0);
    stageB(0, 1); stageB(1, 1);

    for (int i = 0; i < NI; ++i) {
        int t0 = 2 * i;
        bool last = (i == NI - 1);
        bf16x8 bfr[4][2];
        // ================= phases 0..3 : tile t0, buf 0 =================
#pragma unroll
        for (int q = 0; q < 4; ++q) {
            bf16x8 af[2][2];
            if (q == 0) {
                asm volatile("s_waitcnt vmcnt(4)" ::: "memory");
                if (t0 + 1 < NT) stageA(0, t0 + 1);
                asm volatile("s_barrier" ::: "memory");   // ALL waves' tile-t0 loads landed
                // reads must follow the barrier (cross-wave staging confirmation)
#pragma unroll
                for (int n = 0; n < 4; ++n)
#pragma unroll
                    for (int ks = 0; ks < 2; ++ks) {
                        int rb = wn * 64 + n * 16 + rr;
                        int hb = rb >> 7, Lr = rb & 127;
                        int c = ks * 4 + ko;
                        bfr[n][ks] = *(const bf16x8*)((const char*)&Bl[0][hb][0] +
                                     Lr * 128 + ((c ^ (Lr & 7)) * 16));
                    }
#pragma unroll
                for (int mi = 0; mi < 2; ++mi)
#pragma unroll
                    for (int ks = 0; ks < 2; ++ks) {
                        int Lr = (q * 2 + mi) * 16 + rr;
                        int c = ks * 4 + ko;
                        af[mi][ks] = *(const bf16x8*)((const char*)&Al[0][wm][0] +
                                     Lr * 128 + ((c ^ (Lr & 7)) * 16));
                    }
            } else {
#pragma unroll
                for (int mi = 0; mi < 2; ++mi)
#pragma unroll
                    for (int ks = 0; ks < 2; ++ks) {
                        int Lr = (q * 2 + mi) * 16 + rr;
                        int c = ks * 4 + ko;
                        af[mi][ks] = *(const bf16x8*)((const char*)&Al[0][wm][0] +
                                     Lr * 128 + ((c ^ (Lr & 7)) * 16));
                    }
                if (q == 1)      { if (t0 + 1 < NT) stageA(1, t0 + 1); }
                else if (q == 2) { if (t0 + 2 < NT) stageB(0, t0 + 2); }
                else             { if (t0 + 2 < NT) stageB(1, t0 + 2); }
                asm volatile("s_barrier" ::: "memory");
            }
            asm volatile("s_waitcnt lgkmcnt(0)" ::: "memory");
            __builtin_amdgcn_s_setprio(1);
#pragma unroll
            for (int mi = 0; mi < 2; ++mi) {
#pragma unroll
                for (int n = 0; n < 4; ++n) {
                    acc[q * 2 + mi][n] = __builtin_amdgcn_mfma_f32_16x16x32_bf16(
                        af[mi][0], bfr[n][0], acc[q * 2 + mi][n], 0, 0, 0);
                    acc[q * 2 + mi][n] = __builtin_amdgcn_mfma_f32_16x16x32_bf16(
                        af[mi][1], bfr[n][1], acc[q * 2 + mi][n], 0, 0, 0);
                }
            }
            __builtin_amdgcn_s_setprio(0);
            asm volatile("s_barrier" ::: "memory");
        }
        // ================= phases 4..7 : tile t0+1, buf 1 =================
#pragma unroll
        for (int q = 0; q < 4; ++q) {
            bf16x8 af[2][2];
            if (q == 0) {
                if (last) asm volatile("s_waitcnt vmcnt(0)" ::: "memory");
                else      asm volatile("s_waitcnt vmcnt(4)" ::: "memory");
                if (t0 + 2 < NT) stageA(0, t0 + 2);
                asm volatile("s_barrier" ::: "memory");   // tile t0+1 fully landed
#pragma unroll
                for (int n = 0; n < 4; ++n)
#pragma unroll
                    for (int ks = 0; ks < 2; ++ks) {
                        int rb = wn * 64 + n * 16 + rr;
                        int hb = rb >> 7, Lr = rb & 127;
                        int c = ks * 4 + ko;
                        bfr[n][ks] = *(const bf16x8*)((const char*)&Bl[1][hb][0] +
                                     Lr * 128 + ((c ^ (Lr & 7)) * 16));
                    }
#pragma unroll
                for (int mi = 0; mi < 2; ++mi)
#pragma unroll
                    for (int ks = 0; ks < 2; ++ks) {
                        int Lr = (q * 2 + mi) * 16 + rr;
                        int c = ks * 4 + ko;
                        af[mi][ks] = *(const bf16x8*)((const char*)&Al[1][wm][0] +
                                     Lr * 128 + ((c ^ (Lr & 7)) * 16));
                    }
            } else {
#pragma unroll
                for (int mi = 0; mi < 2; ++mi)
#pragma unroll
                    for (int ks = 0; ks < 2; ++ks) {
                        int Lr = (q * 2 + mi) * 16 + rr;
                        int c = ks * 4 + ko;
                        af[mi][ks] = *(const bf16x8*)((const char*)&Al[1][wm][0] +
                                     Lr * 128 + ((c ^ (Lr & 7)) * 16));
                    }
                if (q == 1)      { if (t0 + 2 < NT) stageA(1, t0 + 2); }
                else if (q == 2) { if (t0 + 3 < NT) stageB(0, t0 + 3); }
                else             { if (t0 + 3 < NT) stageB(1, t0 + 3); }
                asm volatile("s_barrier" ::: "memory");
            }
            asm volatile("s_waitcnt lgkmcnt(0)" ::: "memory");
            __builtin_amdgcn_s_setprio(1);
#pragma unroll
            for (int mi = 0; mi < 2; ++mi) {
#pragma unroll
                for (int n = 0; n < 4; ++n) {
                    acc[q * 2 + mi][n] = __builtin_amdgcn_mfma_f32_16x16x32_bf16(
                        af[mi][0], bfr[n][0], acc[q * 2 + mi][n], 0, 0, 0);
                    acc[q * 2 + mi][n] = __builtin_amdgcn_mfma_f32_16x16x32_bf16(
                        af[mi][1], bfr[n][1], acc[q * 2 + mi][n], 0, 0, 0);
                }
            }
            __builtin_amdgcn_s_setprio(0);
            asm volatile("s_barrier" ::: "memory");
        }
    }
    int crow0 = (int)rowA0 + wm * 128;
    int ccol0 = bn * 256 + wn * 64;
#pragma unroll
    for (int m = 0; m < 8; ++m)
#pragma unroll
        for (int n = 0; n < 4; ++n) {
            int col = ccol0 + n * 16 + rr;
            float bsv = bias ? bias[col] : 0.f;
#pragma unroll
            for (int r4 = 0; r4 < 4; ++r4) {
                int row = crow0 + m * 16 + ko * 4 + r4;
                float v = acc[m][n][r4] + bsv;
                if constexpr (sizeof(OT) == 2) {
                    ((ushort*)C)[(size_t)row * N + col] = f2bf(v);
                } else {
                    ((float*)C)[(size_t)row * N + col] = v;
                }
            }
        }
}

extern "C" void kernel_launch(void* const* d_in, const int* in_sizes, int n_in,
                              void* d_out, int out_size, void* d_ws, size_t ws_size,
                              hipStream_t stream) {
    const float* x_in       = (const float*)d_in[0];
    const float* workspace  = (const float*)d_in[1];
    const float* compete_w  = (const float*)d_in[2];
    const float* compete_b  = (const float*)d_in[3];
    const float* write_w    = (const float*)d_in[4];
    const float* write_b    = (const float*)d_in[5];
    const float* in_proj_w  = (const float*)d_in[6];
    const float* in_proj_b  = (const float*)d_in[7];
    const float* out_proj_w = (const float*)d_in[8];
    const float* out_proj_b = (const float*)d_in[9];
    const float* norm_pre_w  = (const float*)d_in[12];
    const float* norm_post_w = (const float*)d_in[13];
    float* xout = (float*)d_out;

    char* base = (char*)d_ws;
    size_t off = 0;
    auto alloc = [&](size_t bytes) {
        void* p = base + off;
        off += (bytes + 255) & ~(size_t)255;
        return p;
    };
    ushort* xb      = (ushort*)alloc((size_t)BL * D * 2);
    float*  qbuf    = (float*) alloc((size_t)BL * D * 4);     // attn_out (f32)
    ushort* qbb     = (ushort*)alloc((size_t)BL * D * 2);     // q bf16
    ushort* ctxb    = (ushort*)alloc((size_t)BL * D * 2);
    float*  logits  = (float*) alloc((size_t)BATCH * NSLOT * LSEQ * 4);
    ushort* xbar    = (ushort*)alloc((size_t)BATCH * NSLOT * D * 2);
    float*  written = (float*) alloc((size_t)BATCH * NSLOT * D * 4);
    float*  wsbuf   = (float*) alloc((size_t)BATCH * NSLOT * D * 4);
    ushort* wsb     = (ushort*)alloc((size_t)BATCH * NSLOT * D * 2);
    ushort* ipb     = (ushort*)alloc((size_t)3 * D * D * 2);
    ushort* wob     = (ushort*)alloc((size_t)D * D * 2);
    ushort* wwb     = (ushort*)alloc((size_t)D * D * 2);
    float*  kb32    = (float*) alloc((size_t)BATCH * NHEAD * NSLOT * HDIM * 4);
    float*  vb32    = (float*) alloc((size_t)BATCH * NHEAD * NSLOT * HDIM * 4);
    (void)ws_size; (void)in_sizes; (void)n_in; (void)out_size;

    conv_bf16_kernel<<<2048, 256, 0, stream>>>((const float4*)in_proj_w, ipb, 3 * D * D / 4);
    conv_bf16_kernel<<<2048, 256, 0, stream>>>((const float4*)out_proj_w, wob, D * D / 4);
    conv_bf16_kernel<<<2048, 256, 0, stream>>>((const float4*)write_w, wwb, D * D / 4);
    conv_bf16_kernel<<<2048, 256, 0, stream>>>((const float4*)x_in, xb, BL * D / 4);

    for (int it = 0; it < 2; ++it) {
        const float* xs = it ? (const float*)xout : x_in;
        logits_kernel<<<BL / 4, 256, 0, stream>>>(xs, compete_w, compete_b, norm_pre_w,
                                                  logits);
        topk_xbar_kernel<<<BATCH * NSLOT, 256, 0, stream>>>(logits, xs, xbar);
        gemm_bt<64><<<dim3(D / 128, 1), 256, 0, stream>>>(xbar, wwb, write_b, written,
                                                          BATCH * NSLOT, D, D,
                                                          (float*)nullptr, (float*)nullptr);
        ws_update_kernel<<<BATCH * NSLOT, 256, 0, stream>>>(written, wsbuf, workspace,
                                                            it == 0 ? 1 : 0, norm_post_w,
                                                            wsbuf, wsb);
        gemm_bt<64><<<dim3(2 * D / 128, 1), 256, 0, stream>>>(wsb, ipb + (size_t)D * D,
                                                              in_proj_b + D, (float*)nullptr,
                                                              BATCH * NSLOT, 2 * D, D,
                                                              kb32, vb32);
        gemm_big<ushort><<<(D / 256) * (BL / 256), 512, 0, stream>>>(xb, ipb, in_proj_b,
                                                                     qbb, BL, D, D);
        attn_kernel<<<BL * NHEAD * 8 / 256, 256, 0, stream>>>(qbb, kb32, vb32, ctxb);
        gemm_big<float><<<(D / 256) * (BL / 256), 512, 0, stream>>>(ctxb, wob, out_proj_b,
                                                                    qbuf, BL, D, D);
        resid_rms_kernel<<<BL, 256, 0, stream>>>(xs, qbuf, norm_post_w, xout, xb);
    }
}

// Round 12
// 602.198 us; speedup vs baseline: 1.4010x; 1.2895x over previous
//
#include <hip/hip_runtime.h>
#include <stdint.h>

#define D 2048
#define LSEQ 2048
#define BATCH 4
#define BL (BATCH * LSEQ)   // 8192 rows
#define NSLOT 16
#define NHEAD 32
#define HDIM 64
#define EPSV 1e-6f

typedef __attribute__((ext_vector_type(8))) short bf16x8;
typedef __attribute__((ext_vector_type(4))) float f32x4;

static __device__ __forceinline__ ushort f2bf(float f) {
    uint32_t u = __float_as_uint(f);
    u += 0x7fffu + ((u >> 16) & 1u);   // RNE
    return (ushort)(u >> 16);
}

static __device__ __forceinline__ float wave_sum(float v) {
#pragma unroll
    for (int off = 32; off > 0; off >>= 1) v += __shfl_xor(v, off, 64);
    return v;
}

static __device__ __forceinline__ void gl_lds16(const void* g, void* l) {
    __builtin_amdgcn_global_load_lds(
        (__attribute__((address_space(1))) uint32_t*)(uintptr_t)g,
        (__attribute__((address_space(3))) uint32_t*)(uint32_t)(uintptr_t)l,
        16, 0, 0);
}

// ---------------- weight convert f32 -> bf16 ----------------
__global__ __launch_bounds__(256) void conv_bf16_kernel(const float4* __restrict__ src,
                                                        ushort* __restrict__ dst, int n4) {
    int i = blockIdx.x * 256 + threadIdx.x;
    int stride = gridDim.x * 256;
    for (; i < n4; i += stride) {
        float4 v = src[i];
        uint2 o;
        o.x = (uint)f2bf(v.x) | ((uint)f2bf(v.y) << 16);
        o.y = (uint)f2bf(v.z) | ((uint)f2bf(v.w) << 16);
        *(uint2*)(dst + (size_t)i * 4) = o;
    }
}

// ---------------- 2048x2048 bf16 transpose (once, for Wq^T) ----------------
__global__ __launch_bounds__(256) void transpose_bf16_kernel(const ushort* __restrict__ src,
                                                             ushort* __restrict__ dst) {
    __shared__ ushort t[64][72];
    int bx = blockIdx.x & 31, by = blockIdx.x >> 5;
    int r0 = by * 64, c0 = bx * 64;
    int tid = threadIdx.x;
    int lr = tid >> 3;
    int lc = (tid & 7) * 8;
#pragma unroll
    for (int p = 0; p < 2; ++p) {
        int rr = p * 32 + lr;
        bf16x8 v = *(const bf16x8*)(src + (size_t)(r0 + rr) * 2048 + c0 + lc);
#pragma unroll
        for (int j = 0; j < 8; ++j) t[lc + j][rr] = (ushort)v[j];
    }
    __syncthreads();
#pragma unroll
    for (int p = 0; p < 2; ++p) {
        int rr = p * 32 + lr;
        *(bf16x8*)(dst + (size_t)(c0 + rr) * 2048 + r0 + lc) = *(const bf16x8*)&t[rr][lc];
    }
}

// ---------------- logits v4: 4 rows/block, BIT-EXACT to the R4-passing kernel ----
// DO NOT change any arithmetic here: logits bits feed top-k (an order-statistic
// discontinuity); R5 failed from a 1e-7-level summation-order change.
__global__ __launch_bounds__(256) void logits_kernel(
    const float* __restrict__ x, const float* __restrict__ cw,
    const float* __restrict__ cb, const float* __restrict__ wpre,
    float* __restrict__ logits_t) {
    int blk = blockIdx.x;              // 2048 blocks, 4 rows each
    int b = blk >> 9;                  // 512 blocks per batch
    int l0 = (blk & 511) << 2;
    int tid = threadIdx.x;
    int i0 = tid * 8;
    float4 w0 = *(const float4*)(wpre + i0);
    float4 w1 = *(const float4*)(wpre + i0 + 4);
    float wv[8] = {w0.x, w0.y, w0.z, w0.w, w1.x, w1.y, w1.z, w1.w};
    float xw[4][8];
    float ss[4];
#pragma unroll
    for (int r = 0; r < 4; ++r) {
        const float* xr = x + ((size_t)(b * LSEQ + l0 + r)) * D;
        float4 a0 = *(const float4*)(xr + i0);
        float4 a1 = *(const float4*)(xr + i0 + 4);
        float xv[8] = {a0.x, a0.y, a0.z, a0.w, a1.x, a1.y, a1.z, a1.w};
        float s0 = 0.f;
#pragma unroll
        for (int j = 0; j < 8; ++j) { s0 += xv[j] * xv[j]; xw[r][j] = xv[j] * wv[j]; }
        ss[r] = s0;
    }
    float acc[NSLOT][4];
#pragma unroll
    for (int s = 0; s < NSLOT; ++s) {
        const float* cwr = cw + (size_t)s * D + i0;
        float4 c0 = *(const float4*)(cwr);
        float4 c1 = *(const float4*)(cwr + 4);
#pragma unroll
        for (int r = 0; r < 4; ++r)
            acc[s][r] = xw[r][0] * c0.x + xw[r][1] * c0.y + xw[r][2] * c0.z + xw[r][3] * c0.w +
                        xw[r][4] * c1.x + xw[r][5] * c1.y + xw[r][6] * c1.z + xw[r][7] * c1.w;
    }
#pragma unroll
    for (int r = 0; r < 4; ++r) ss[r] = wave_sum(ss[r]);
#pragma unroll
    for (int s = 0; s < NSLOT; ++s)
#pragma unroll
        for (int r = 0; r < 4; ++r) acc[s][r] = wave_sum(acc[s][r]);
    __shared__ float red[4][NSLOT][4];
    __shared__ float redss[4][4];
    int lane = tid & 63, w = tid >> 6;
    if (lane == 0) {
#pragma unroll
        for (int r = 0; r < 4; ++r) redss[w][r] = ss[r];
#pragma unroll
        for (int s = 0; s < NSLOT; ++s)
#pragma unroll
            for (int r = 0; r < 4; ++r) red[w][s][r] = acc[s][r];
    }
    __syncthreads();
    if (tid < 64) {
        int s = tid >> 2, r = tid & 3;
        float tot = red[0][s][r] + red[1][s][r] + red[2][s][r] + red[3][s][r];
        float s2 = redss[0][r] + redss[1][r] + redss[2][r] + redss[3][r];
        float rsq = 1.0f / sqrtf(s2 * (1.0f / (float)D) + EPSV);
        logits_t[((size_t)(b * NSLOT + s)) * LSEQ + l0 + r] = tot * rsq + cb[s];
    }
}

// ---------------- top-4 + softmax + weighted row gather (xbar, bf16) ----------------
__global__ __launch_bounds__(256) void topk_xbar_kernel(
    const float* __restrict__ logits_t, const float* __restrict__ x,
    ushort* __restrict__ xbar_b) {
    int bs = blockIdx.x;
    int b = bs >> 4;
    const float* lr = logits_t + (size_t)bs * LSEQ;
    int tid = threadIdx.x, lane = tid & 63, w = tid >> 6;
    __shared__ float rv[4];
    __shared__ int ri[4];
    __shared__ float selv[4];
    __shared__ int seli[4];
    int i0 = tid * 8;
    float myv[8];
#pragma unroll
    for (int j = 0; j < 8; ++j) myv[j] = lr[i0 + j];
    int chosen[4];
    for (int p = 0; p < 4; ++p) {
        float bv = -3.4e38f;
        int bi = 0x7fffffff;
#pragma unroll
        for (int j = 0; j < 8; ++j) {
            int i = i0 + j;
            bool skip = false;
            for (int q = 0; q < p; ++q) skip = skip || (i == chosen[q]);
            float v = myv[j];
            if (!skip && (v > bv || (v == bv && i < bi))) { bv = v; bi = i; }
        }
#pragma unroll
        for (int off = 1; off < 64; off <<= 1) {
            float ov = __shfl_xor(bv, off, 64);
            int oi = __shfl_xor(bi, off, 64);
            if (ov > bv || (ov == bv && oi < bi)) { bv = ov; bi = oi; }
        }
        if (lane == 0) { rv[w] = bv; ri[w] = bi; }
        __syncthreads();
        if (tid == 0) {
            float fv = rv[0];
            int fi = ri[0];
            for (int q = 1; q < 4; ++q)
                if (rv[q] > fv || (rv[q] == fv && ri[q] < fi)) { fv = rv[q]; fi = ri[q]; }
            selv[p] = fv;
            seli[p] = fi;
        }
        __syncthreads();
        chosen[p] = seli[p];
    }
    float vals[4];
#pragma unroll
    for (int p = 0; p < 4; ++p) vals[p] = selv[p];
    float mx = vals[0];   // first pick is the max
    float e[4], den = 0.f;
#pragma unroll
    for (int p = 0; p < 4; ++p) { e[p] = expf(vals[p] - mx); den += e[p]; }
    float inv = 1.0f / den;
    const float* xr0 = x + ((size_t)b * LSEQ + chosen[0]) * D;
    const float* xr1 = x + ((size_t)b * LSEQ + chosen[1]) * D;
    const float* xr2 = x + ((size_t)b * LSEQ + chosen[2]) * D;
    const float* xr3 = x + ((size_t)b * LSEQ + chosen[3]) * D;
    float s[8];
#pragma unroll
    for (int j = 0; j < 8; ++j) {
        int i = i0 + j;
        s[j] = (e[0] * xr0[i] + e[1] * xr1[i] + e[2] * xr2[i] + e[3] * xr3[i]) * inv;
    }
    uint4 o;
    o.x = (uint)f2bf(s[0]) | ((uint)f2bf(s[1]) << 16);
    o.y = (uint)f2bf(s[2]) | ((uint)f2bf(s[3]) << 16);
    o.z = (uint)f2bf(s[4]) | ((uint)f2bf(s[5]) << 16);
    o.w = (uint)f2bf(s[6]) | ((uint)f2bf(s[7]) << 16);
    *(uint4*)(xbar_b + (size_t)bs * D + i0) = o;
}

// ---------------- ws = rms(ws_prev + written) (+bf16 copy) ----------------
__global__ __launch_bounds__(256) void ws_update_kernel(
    const float* __restrict__ written, const float* __restrict__ ws_prev,
    const float* __restrict__ workspace0, int first,
    const float* __restrict__ wpost, float* __restrict__ ws_out,
    ushort* __restrict__ ws_b) {
    int bs = blockIdx.x;
    int s = bs & (NSLOT - 1);
    int tid = threadIdx.x;
    int i0 = tid * 8;
    const float* prev = first ? (workspace0 + (size_t)s * D) : (ws_prev + (size_t)bs * D);
    const float* wr = written + (size_t)bs * D;
    float4 p0 = *(const float4*)(prev + i0);
    float4 p1 = *(const float4*)(prev + i0 + 4);
    float4 q0 = *(const float4*)(wr + i0);
    float4 q1 = *(const float4*)(wr + i0 + 4);
    float t[8] = {p0.x + q0.x, p0.y + q0.y, p0.z + q0.z, p0.w + q0.w,
                  p1.x + q1.x, p1.y + q1.y, p1.z + q1.z, p1.w + q1.w};
    float ss = 0.f;
#pragma unroll
    for (int j = 0; j < 8; ++j) ss += t[j] * t[j];
    ss = wave_sum(ss);
    __shared__ float sb[4];
    if ((tid & 63) == 0) sb[tid >> 6] = ss;
    __syncthreads();
    ss = sb[0] + sb[1] + sb[2] + sb[3];
    float rsq = 1.0f / sqrtf(ss * (1.0f / (float)D) + EPSV);
    float4 w0 = *(const float4*)(wpost + i0);
    float4 w1 = *(const float4*)(wpost + i0 + 4);
    float wv[8] = {w0.x, w0.y, w0.z, w0.w, w1.x, w1.y, w1.z, w1.w};
    float o[8];
#pragma unroll
    for (int j = 0; j < 8; ++j) o[j] = t[j] * rsq * wv[j];
    float4 r0 = {o[0], o[1], o[2], o[3]};
    float4 r1 = {o[4], o[5], o[6], o[7]};
    *(float4*)(ws_out + (size_t)bs * D + i0) = r0;
    *(float4*)(ws_out + (size_t)bs * D + i0 + 4) = r1;
    uint4 ob;
    ob.x = (uint)f2bf(o[0]) | ((uint)f2bf(o[1]) << 16);
    ob.y = (uint)f2bf(o[2]) | ((uint)f2bf(o[3]) << 16);
    ob.z = (uint)f2bf(o[4]) | ((uint)f2bf(o[5]) << 16);
    ob.w = (uint)f2bf(o[6]) | ((uint)f2bf(o[7]) << 16);
    *(uint4*)(ws_b + (size_t)bs * D + i0) = ob;
}

// ---------------- x = rms(x + attn_out) (+bf16 copy) ----------------
__global__ __launch_bounds__(256) void resid_rms_kernel(
    const float* __restrict__ x_src, const float* __restrict__ ao,
    const float* __restrict__ wpost, float* __restrict__ x_dst,
    ushort* __restrict__ xb) {
    int row = blockIdx.x;
    int tid = threadIdx.x;
    int i0 = tid * 8;
    const float* xr = x_src + (size_t)row * D;
    const float* ar = ao + (size_t)row * D;
    float4 p0 = *(const float4*)(xr + i0);
    float4 p1 = *(const float4*)(xr + i0 + 4);
    float4 q0 = *(const float4*)(ar + i0);
    float4 q1 = *(const float4*)(ar + i0 + 4);
    float t[8] = {p0.x + q0.x, p0.y + q0.y, p0.z + q0.z, p0.w + q0.w,
                  p1.x + q1.x, p1.y + q1.y, p1.z + q1.z, p1.w + q1.w};
    float ss = 0.f;
#pragma unroll
    for (int j = 0; j < 8; ++j) ss += t[j] * t[j];
    ss = wave_sum(ss);
    __shared__ float sb[4];
    if ((tid & 63) == 0) sb[tid >> 6] = ss;
    __syncthreads();
    ss = sb[0] + sb[1] + sb[2] + sb[3];
    float rsq = 1.0f / sqrtf(ss * (1.0f / (float)D) + EPSV);
    float4 w0 = *(const float4*)(wpost + i0);
    float4 w1 = *(const float4*)(wpost + i0 + 4);
    float wv[8] = {w0.x, w0.y, w0.z, w0.w, w1.x, w1.y, w1.z, w1.w};
    float o[8];
#pragma unroll
    for (int j = 0; j < 8; ++j) o[j] = t[j] * rsq * wv[j];
    float4 r0 = {o[0], o[1], o[2], o[3]};
    float4 r1 = {o[4], o[5], o[6], o[7]};
    *(float4*)(x_dst + (size_t)row * D + i0) = r0;
    *(float4*)(x_dst + (size_t)row * D + i0 + 4) = r1;
    uint4 ob;
    ob.x = (uint)f2bf(o[0]) | ((uint)f2bf(o[1]) << 16);
    ob.y = (uint)f2bf(o[2]) | ((uint)f2bf(o[3]) << 16);
    ob.z = (uint)f2bf(o[4]) | ((uint)f2bf(o[5]) << 16);
    ob.w = (uint)f2bf(o[6]) | ((uint)f2bf(o[7]) << 16);
    *(uint4*)(xb + (size_t)row * D + i0) = ob;
}

// ---------------- cbias[b*512+hs] = sum_d K[b,h,s,d]*bq[h*64+d] ----------------
__global__ __launch_bounds__(256) void cbias_kernel(const ushort* __restrict__ kb16,
                                                    const float* __restrict__ bq,
                                                    float* __restrict__ cb) {
    int i = blockIdx.x * 256 + threadIdx.x;   // 0..2047
    int hs = i & 511;
    int h = hs >> 4;
    const ushort* kr = kb16 + (size_t)i * 64;
    const float* bb = bq + h * 64;
    float acc = 0.f;
#pragma unroll
    for (int d = 0; d < 64; ++d)
        acc += __uint_as_float(((uint)kr[d]) << 16) * bb[d];
    cb[i] = acc;
}

// ---------------- grouped 16x64 GEMM: per (b,h): C[16x2048] = A[16x64] @ Bslice^T --
// A at Abase + g*16*64 (bf16 row-major). Bw[n=j][k=d] = Bmat[j*2048 + h*64 + d].
// TRANS=0: Cout[(g*16+s)*2048 + j]   (K~: rows b*512+hs, stride 2048)
// TRANS=1: Cout[j*2048 + g*16 + s]   (W~^T: row j, cols b*512+hs)
template <int TRANS>
__global__ __launch_bounds__(256) void grouped16_kernel(
    const ushort* __restrict__ Abase, const ushort* __restrict__ Bmat,
    ushort* __restrict__ Cout) {
    int blk = blockIdx.x;           // g*8 + nt   (1024 blocks)
    int g = blk >> 3;               // 0..127 = b*32+h
    int nt = blk & 7;
    int h = g & 31;
    int hoff = h * 64;
    int tid = threadIdx.x, lane = tid & 63, wv = tid >> 6;
    int j0 = nt * 256 + wv * 64;
    int rr = lane & 15, ko = lane >> 4;
    const ushort* A = Abase + (size_t)g * 16 * 64;
    bf16x8 af0 = *(const bf16x8*)(A + rr * 64 + ko * 8);
    bf16x8 af1 = *(const bf16x8*)(A + rr * 64 + 32 + ko * 8);
    f32x4 acc[4];
    f32x4 zero = {0.f, 0.f, 0.f, 0.f};
#pragma unroll
    for (int nf = 0; nf < 4; ++nf) acc[nf] = zero;
#pragma unroll
    for (int nf = 0; nf < 4; ++nf) {
        int j = j0 + nf * 16 + rr;
        bf16x8 b0 = *(const bf16x8*)(Bmat + (size_t)j * 2048 + hoff + ko * 8);
        bf16x8 b1 = *(const bf16x8*)(Bmat + (size_t)j * 2048 + hoff + 32 + ko * 8);
        acc[nf] = __builtin_amdgcn_mfma_f32_16x16x32_bf16(af0, b0, acc[nf], 0, 0, 0);
        acc[nf] = __builtin_amdgcn_mfma_f32_16x16x32_bf16(af1, b1, acc[nf], 0, 0, 0);
    }
#pragma unroll
    for (int nf = 0; nf < 4; ++nf)
#pragma unroll
        for (int r = 0; r < 4; ++r) {
            int s = ko * 4 + r;
            int j = j0 + nf * 16 + rr;
            ushort v = f2bf(acc[nf][r]);
            if (TRANS) Cout[(size_t)j * 2048 + g * 16 + s] = v;
            else       Cout[(size_t)(g * 16 + s) * 2048 + j] = v;
        }
}

// ---------------- attn softmax: A_att[l, hs] = softmax_s((qlog+cbias)*0.125) ------
__global__ __launch_bounds__(256) void attn_sm_kernel(
    const float* __restrict__ qlog, const float* __restrict__ cb,
    ushort* __restrict__ aatt) {
    int blk = blockIdx.x;               // 1024 blocks x 8 rows
    int tid = threadIdx.x;
    int l = blk * 8 + (tid >> 5);
    int b = l >> 11;
    int h = tid & 31;
    const float* q = qlog + (size_t)l * 512 + h * 16;
    const float* c = cb + b * 512 + h * 16;
    float p[16];
#pragma unroll
    for (int i = 0; i < 16; i += 4) {
        float4 v = *(const float4*)(q + i);
        float4 cc = *(const float4*)(c + i);
        p[i] = v.x + cc.x; p[i + 1] = v.y + cc.y;
        p[i + 2] = v.z + cc.z; p[i + 3] = v.w + cc.w;
    }
    float mx = p[0];
#pragma unroll
    for (int s = 1; s < 16; ++s) mx = fmaxf(mx, p[s]);
    float den = 0.f;
#pragma unroll
    for (int s = 0; s < 16; ++s) { p[s] = __expf((p[s] - mx) * 0.125f); den += p[s]; }
    float inv = 1.0f / den;
    uint4 o[2];
    uint* ow = (uint*)o;
#pragma unroll
    for (int i = 0; i < 8; ++i)
        ow[i] = (uint)f2bf(p[2 * i] * inv) | ((uint)f2bf(p[2 * i + 1] * inv) << 16);
    ushort* dst = aatt + (size_t)l * 512 + h * 16;
    *(uint4*)dst = o[0];
    *(uint4*)(dst + 8) = o[1];
}

// ---------------- bf16 MFMA GEMM: C[m,n] = sum_k A[m,k]*Bw[n,k] + bias[n] ----------
// bOff: per-batch element offset added to Bw (batch = row-tile>>11); bStride: B row
// stride in elements (normally == K). kv mode (kvk!=null) writes per-head bf16 K/V.
template <int BM>
__global__ __launch_bounds__(256) void gemm_bt(
    const ushort* __restrict__ A, const ushort* __restrict__ Bw,
    const float* __restrict__ bias, float* __restrict__ C,
    int M, int N, int K, ushort* __restrict__ kvk, ushort* __restrict__ kvv,
    size_t bOff, int bStride) {
    constexpr int BN = 128, BK = 32;
    constexpr int MF = BM / 32;
    constexpr int APASS = (BM * BK / 8) / 256;
    __shared__ short lds[2][(BM + BN) * BK];
    int tid = threadIdx.x;
    int lane = tid & 63, w = tid >> 6;
    int wr = w >> 1, wc = w & 1;
    int tn = blockIdx.x * BN;
    int tm = blockIdx.y * BM;
    Bw += (size_t)(tm >> 11) * bOff;
    f32x4 acc[MF][4];
    f32x4 zero = {0.f, 0.f, 0.f, 0.f};
#pragma unroll
    for (int m = 0; m < MF; ++m)
#pragma unroll
        for (int n = 0; n < 4; ++n) acc[m][n] = zero;
    int NT = K / BK;

    auto stage = [&](int buf, int t) {
        int kt = t * BK;
#pragma unroll
        for (int p = 0; p < APASS; ++p) {
            int cb = p * 256 + w * 64;
            int c = cb + lane;
            int r = c >> 2;
            int k8 = (c & 3) * 8;
            int gr = tm + r;
            if (gr >= M) gr = M - 1;
            gl_lds16(A + (size_t)gr * K + kt + k8, (void*)&lds[buf][cb * 8]);
        }
#pragma unroll
        for (int p = 0; p < 2; ++p) {
            int cb = p * 256 + w * 64;
            int c = cb + lane;
            int r = c >> 2;
            int k8 = (c & 3) * 8;
            gl_lds16(Bw + (size_t)(tn + r) * bStride + kt + k8,
                     (void*)&lds[buf][BM * BK + cb * 8]);
        }
    };
    stage(0, 0);
    for (int t = 0; t < NT; ++t) {
        __syncthreads();
        if (t + 1 < NT) stage((t + 1) & 1, t + 1);
        const short* Ab = &lds[t & 1][0];
        const short* Bb = &lds[t & 1][BM * BK];
        int ko = (lane >> 4) * 8;
        int rr = lane & 15;
        bf16x8 af[MF], bfr[4];
#pragma unroll
        for (int m = 0; m < MF; ++m)
            af[m] = *(const bf16x8*)&Ab[(wr * (MF * 16) + m * 16 + rr) * BK + ko];
#pragma unroll
        for (int n = 0; n < 4; ++n)
            bfr[n] = *(const bf16x8*)&Bb[(wc * 64 + n * 16 + rr) * BK + ko];
#pragma unroll
        for (int m = 0; m < MF; ++m)
#pragma unroll
            for (int n = 0; n < 4; ++n)
                acc[m][n] = __builtin_amdgcn_mfma_f32_16x16x32_bf16(af[m], bfr[n],
                                                                    acc[m][n], 0, 0, 0);
    }
#pragma unroll
    for (int m = 0; m < MF; ++m) {
#pragma unroll
        for (int n = 0; n < 4; ++n) {
            int col = tn + wc * 64 + n * 16 + (lane & 15);
            float bsv = bias ? bias[col] : 0.f;
#pragma unroll
            for (int r = 0; r < 4; ++r) {
                int rowi = tm + wr * (MF * 16) + m * 16 + (lane >> 4) * 4 + r;
                if (rowi >= M) continue;
                float v = acc[m][n][r] + bsv;
                if (kvk) {
                    // kv mode: row = b*16+s, col<2048 -> K head h, else V
                    int b = rowi >> 4, s = rowi & 15;
                    int c2 = (col < 2048) ? col : col - 2048;
                    int h = c2 >> 6, d = c2 & 63;
                    size_t dst = (((size_t)(b * NHEAD + h)) * NSLOT + s) * HDIM + d;
                    if (col < 2048) kvk[dst] = f2bf(v);
                    else            kvv[dst] = f2bf(v);
                } else {
                    C[(size_t)rowi * N + col] = v;
                }
            }
        }
    }
}

extern "C" void kernel_launch(void* const* d_in, const int* in_sizes, int n_in,
                              void* d_out, int out_size, void* d_ws, size_t ws_size,
                              hipStream_t stream) {
    const float* x_in       = (const float*)d_in[0];
    const float* workspace  = (const float*)d_in[1];
    const float* compete_w  = (const float*)d_in[2];
    const float* compete_b  = (const float*)d_in[3];
    const float* write_w    = (const float*)d_in[4];
    const float* write_b    = (const float*)d_in[5];
    const float* in_proj_w  = (const float*)d_in[6];
    const float* in_proj_b  = (const float*)d_in[7];
    const float* out_proj_w = (const float*)d_in[8];
    const float* out_proj_b = (const float*)d_in[9];
    const float* norm_pre_w  = (const float*)d_in[12];
    const float* norm_post_w = (const float*)d_in[13];
    float* xout = (float*)d_out;

    char* base = (char*)d_ws;
    size_t off = 0;
    auto alloc = [&](size_t bytes) {
        void* p = base + off;
        off += (bytes + 255) & ~(size_t)255;
        return p;
    };
    ushort* xb      = (ushort*)alloc((size_t)BL * D * 2);
    float*  qbuf    = (float*) alloc((size_t)BL * D * 4);     // x_b (f32)
    float*  logits  = (float*) alloc((size_t)BATCH * NSLOT * LSEQ * 4);
    ushort* xbar    = (ushort*)alloc((size_t)BATCH * NSLOT * D * 2);
    float*  written = (float*) alloc((size_t)BATCH * NSLOT * D * 4);
    float*  wsbuf   = (float*) alloc((size_t)BATCH * NSLOT * D * 4);
    ushort* wsb     = (ushort*)alloc((size_t)BATCH * NSLOT * D * 2);
    ushort* ipb     = (ushort*)alloc((size_t)3 * D * D * 2);
    ushort* wob     = (ushort*)alloc((size_t)D * D * 2);
    ushort* wwb     = (ushort*)alloc((size_t)D * D * 2);
    ushort* wqt     = (ushort*)alloc((size_t)D * D * 2);      // Wq^T bf16
    ushort* kb16    = (ushort*)alloc((size_t)BATCH * NHEAD * NSLOT * HDIM * 2);
    ushort* vb16    = (ushort*)alloc((size_t)BATCH * NHEAD * NSLOT * HDIM * 2);
    ushort* ktil    = (ushort*)alloc((size_t)BATCH * 512 * D * 2);   // K~ rows b*512+hs
    ushort* wtilT   = (ushort*)alloc((size_t)D * BATCH * 512 * 2);   // W~^T rows j
    float*  qlog    = (float*) alloc((size_t)BL * 512 * 4);
    ushort* aatt    = (ushort*)alloc((size_t)BL * 512 * 2);
    float*  cbias   = (float*) alloc((size_t)BATCH * 512 * 4);
    (void)ws_size; (void)in_sizes; (void)n_in; (void)out_size;

    conv_bf16_kernel<<<2048, 256, 0, stream>>>((const float4*)in_proj_w, ipb, 3 * D * D / 4);
    conv_bf16_kernel<<<2048, 256, 0, stream>>>((const float4*)out_proj_w, wob, D * D / 4);
    conv_bf16_kernel<<<2048, 256, 0, stream>>>((const float4*)write_w, wwb, D * D / 4);
    conv_bf16_kernel<<<2048, 256, 0, stream>>>((const float4*)x_in, xb, BL * D / 4);
    transpose_bf16_kernel<<<1024, 256, 0, stream>>>(ipb, wqt);   // Wq^T (q rows 0..D)

    for (int it = 0; it < 2; ++it) {
        const float* xs = it ? (const float*)xout : x_in;
        logits_kernel<<<BL / 4, 256, 0, stream>>>(xs, compete_w, compete_b, norm_pre_w,
                                                  logits);
        topk_xbar_kernel<<<BATCH * NSLOT, 256, 0, stream>>>(logits, xs, xbar);
        gemm_bt<64><<<dim3(D / 128, 1), 256, 0, stream>>>(xbar, wwb, write_b, written,
                                                          BATCH * NSLOT, D, D,
                                                          (ushort*)nullptr, (ushort*)nullptr,
                                                          0, D);
        ws_update_kernel<<<BATCH * NSLOT, 256, 0, stream>>>(written, wsbuf, workspace,
                                                            it == 0 ? 1 : 0, norm_post_w,
                                                            wsbuf, wsb);
        gemm_bt<64><<<dim3(2 * D / 128, 1), 256, 0, stream>>>(wsb, ipb + (size_t)D * D,
                                                              in_proj_b + D, (float*)nullptr,
                                                              BATCH * NSLOT, 2 * D, D,
                                                              kb16, vb16, 0, D);
        cbias_kernel<<<8, 256, 0, stream>>>(kb16, in_proj_b, cbias);
        grouped16_kernel<0><<<1024, 256, 0, stream>>>(kb16, wqt, ktil);
        grouped16_kernel<1><<<1024, 256, 0, stream>>>(vb16, wob, wtilT);
        // qlog[l, hs] = xb[l,:] . K~[b,hs,:]
        gemm_bt<128><<<dim3(512 / 128, BL / 128), 256, 0, stream>>>(
            xb, ktil, (const float*)nullptr, qlog, BL, 512, D,
            (ushort*)nullptr, (ushort*)nullptr, (size_t)512 * D, D);
        attn_sm_kernel<<<BL / 8, 256, 0, stream>>>(qlog, cbias, aatt);
        // x_b[l, j] = sum_hs aatt[l,hs] * W~T[j, b*512+hs] + out_proj_b[j]
        gemm_bt<128><<<dim3(D / 128, BL / 128), 256, 0, stream>>>(
            aatt, wtilT, out_proj_b, qbuf, BL, D, 512,
            (ushort*)nullptr, (ushort*)nullptr, (size_t)512, D);
        resid_rms_kernel<<<BL, 256, 0, stream>>>(xs, qbuf, norm_post_w, xout, xb);
    }
}

// Round 13
// 599.633 us; speedup vs baseline: 1.4070x; 1.0043x over previous
//
#include <hip/hip_runtime.h>
#include <stdint.h>

#define D 2048
#define LSEQ 2048
#define BATCH 4
#define BL (BATCH * LSEQ)   // 8192 rows
#define NSLOT 16
#define NHEAD 32
#define HDIM 64
#define EPSV 1e-6f

typedef __attribute__((ext_vector_type(8))) short bf16x8;
typedef __attribute__((ext_vector_type(4))) float f32x4;

static __device__ __forceinline__ ushort f2bf(float f) {
    uint32_t u = __float_as_uint(f);
    u += 0x7fffu + ((u >> 16) & 1u);   // RNE
    return (ushort)(u >> 16);
}

static __device__ __forceinline__ float wave_sum(float v) {
#pragma unroll
    for (int off = 32; off > 0; off >>= 1) v += __shfl_xor(v, off, 64);
    return v;
}

static __device__ __forceinline__ void gl_lds16(const void* g, void* l) {
    __builtin_amdgcn_global_load_lds(
        (__attribute__((address_space(1))) uint32_t*)(uintptr_t)g,
        (__attribute__((address_space(3))) uint32_t*)(uint32_t)(uintptr_t)l,
        16, 0, 0);
}

// ---------------- weight convert f32 -> bf16 ----------------
__global__ __launch_bounds__(256) void conv_bf16_kernel(const float4* __restrict__ src,
                                                        ushort* __restrict__ dst, int n4) {
    int i = blockIdx.x * 256 + threadIdx.x;
    int stride = gridDim.x * 256;
    for (; i < n4; i += stride) {
        float4 v = src[i];
        uint2 o;
        o.x = (uint)f2bf(v.x) | ((uint)f2bf(v.y) << 16);
        o.y = (uint)f2bf(v.z) | ((uint)f2bf(v.w) << 16);
        *(uint2*)(dst + (size_t)i * 4) = o;
    }
}

// ---------------- 2048x2048 bf16 transpose (once, for Wq^T) ----------------
__global__ __launch_bounds__(256) void transpose_bf16_kernel(const ushort* __restrict__ src,
                                                             ushort* __restrict__ dst) {
    __shared__ ushort t[64][72];
    int bx = blockIdx.x & 31, by = blockIdx.x >> 5;
    int r0 = by * 64, c0 = bx * 64;
    int tid = threadIdx.x;
    int lr = tid >> 3;
    int lc = (tid & 7) * 8;
#pragma unroll
    for (int p = 0; p < 2; ++p) {
        int rr = p * 32 + lr;
        bf16x8 v = *(const bf16x8*)(src + (size_t)(r0 + rr) * 2048 + c0 + lc);
#pragma unroll
        for (int j = 0; j < 8; ++j) t[lc + j][rr] = (ushort)v[j];
    }
    __syncthreads();
#pragma unroll
    for (int p = 0; p < 2; ++p) {
        int rr = p * 32 + lr;
        *(bf16x8*)(dst + (size_t)(c0 + rr) * 2048 + r0 + lc) = *(const bf16x8*)&t[rr][lc];
    }
}

// ---------------- logits v4: 4 rows/block, BIT-EXACT to the R4-passing kernel ----
// DO NOT change any arithmetic here: logits bits feed top-k (an order-statistic
// discontinuity); R5 failed from a 1e-7-level summation-order change.
__global__ __launch_bounds__(256) void logits_kernel(
    const float* __restrict__ x, const float* __restrict__ cw,
    const float* __restrict__ cb, const float* __restrict__ wpre,
    float* __restrict__ logits_t) {
    int blk = blockIdx.x;              // 2048 blocks, 4 rows each
    int b = blk >> 9;                  // 512 blocks per batch
    int l0 = (blk & 511) << 2;
    int tid = threadIdx.x;
    int i0 = tid * 8;
    float4 w0 = *(const float4*)(wpre + i0);
    float4 w1 = *(const float4*)(wpre + i0 + 4);
    float wv[8] = {w0.x, w0.y, w0.z, w0.w, w1.x, w1.y, w1.z, w1.w};
    float xw[4][8];
    float ss[4];
#pragma unroll
    for (int r = 0; r < 4; ++r) {
        const float* xr = x + ((size_t)(b * LSEQ + l0 + r)) * D;
        float4 a0 = *(const float4*)(xr + i0);
        float4 a1 = *(const float4*)(xr + i0 + 4);
        float xv[8] = {a0.x, a0.y, a0.z, a0.w, a1.x, a1.y, a1.z, a1.w};
        float s0 = 0.f;
#pragma unroll
        for (int j = 0; j < 8; ++j) { s0 += xv[j] * xv[j]; xw[r][j] = xv[j] * wv[j]; }
        ss[r] = s0;
    }
    float acc[NSLOT][4];
#pragma unroll
    for (int s = 0; s < NSLOT; ++s) {
        const float* cwr = cw + (size_t)s * D + i0;
        float4 c0 = *(const float4*)(cwr);
        float4 c1 = *(const float4*)(cwr + 4);
#pragma unroll
        for (int r = 0; r < 4; ++r)
            acc[s][r] = xw[r][0] * c0.x + xw[r][1] * c0.y + xw[r][2] * c0.z + xw[r][3] * c0.w +
                        xw[r][4] * c1.x + xw[r][5] * c1.y + xw[r][6] * c1.z + xw[r][7] * c1.w;
    }
#pragma unroll
    for (int r = 0; r < 4; ++r) ss[r] = wave_sum(ss[r]);
#pragma unroll
    for (int s = 0; s < NSLOT; ++s)
#pragma unroll
        for (int r = 0; r < 4; ++r) acc[s][r] = wave_sum(acc[s][r]);
    __shared__ float red[4][NSLOT][4];
    __shared__ float redss[4][4];
    int lane = tid & 63, w = tid >> 6;
    if (lane == 0) {
#pragma unroll
        for (int r = 0; r < 4; ++r) redss[w][r] = ss[r];
#pragma unroll
        for (int s = 0; s < NSLOT; ++s)
#pragma unroll
            for (int r = 0; r < 4; ++r) red[w][s][r] = acc[s][r];
    }
    __syncthreads();
    if (tid < 64) {
        int s = tid >> 2, r = tid & 3;
        float tot = red[0][s][r] + red[1][s][r] + red[2][s][r] + red[3][s][r];
        float s2 = redss[0][r] + redss[1][r] + redss[2][r] + redss[3][r];
        float rsq = 1.0f / sqrtf(s2 * (1.0f / (float)D) + EPSV);
        logits_t[((size_t)(b * NSLOT + s)) * LSEQ + l0 + r] = tot * rsq + cb[s];
    }
}

// ---------------- top-4 + softmax + weighted row gather (xbar, bf16) ----------------
__global__ __launch_bounds__(256) void topk_xbar_kernel(
    const float* __restrict__ logits_t, const float* __restrict__ x,
    ushort* __restrict__ xbar_b) {
    int bs = blockIdx.x;
    int b = bs >> 4;
    const float* lr = logits_t + (size_t)bs * LSEQ;
    int tid = threadIdx.x, lane = tid & 63, w = tid >> 6;
    __shared__ float rv[4];
    __shared__ int ri[4];
    __shared__ float selv[4];
    __shared__ int seli[4];
    int i0 = tid * 8;
    float myv[8];
#pragma unroll
    for (int j = 0; j < 8; ++j) myv[j] = lr[i0 + j];
    int chosen[4];
    for (int p = 0; p < 4; ++p) {
        float bv = -3.4e38f;
        int bi = 0x7fffffff;
#pragma unroll
        for (int j = 0; j < 8; ++j) {
            int i = i0 + j;
            bool skip = false;
            for (int q = 0; q < p; ++q) skip = skip || (i == chosen[q]);
            float v = myv[j];
            if (!skip && (v > bv || (v == bv && i < bi))) { bv = v; bi = i; }
        }
#pragma unroll
        for (int off = 1; off < 64; off <<= 1) {
            float ov = __shfl_xor(bv, off, 64);
            int oi = __shfl_xor(bi, off, 64);
            if (ov > bv || (ov == bv && oi < bi)) { bv = ov; bi = oi; }
        }
        if (lane == 0) { rv[w] = bv; ri[w] = bi; }
        __syncthreads();
        if (tid == 0) {
            float fv = rv[0];
            int fi = ri[0];
            for (int q = 1; q < 4; ++q)
                if (rv[q] > fv || (rv[q] == fv && ri[q] < fi)) { fv = rv[q]; fi = ri[q]; }
            selv[p] = fv;
            seli[p] = fi;
        }
        __syncthreads();
        chosen[p] = seli[p];
    }
    float vals[4];
#pragma unroll
    for (int p = 0; p < 4; ++p) vals[p] = selv[p];
    float mx = vals[0];   // first pick is the max
    float e[4], den = 0.f;
#pragma unroll
    for (int p = 0; p < 4; ++p) { e[p] = expf(vals[p] - mx); den += e[p]; }
    float inv = 1.0f / den;
    const float* xr0 = x + ((size_t)b * LSEQ + chosen[0]) * D;
    const float* xr1 = x + ((size_t)b * LSEQ + chosen[1]) * D;
    const float* xr2 = x + ((size_t)b * LSEQ + chosen[2]) * D;
    const float* xr3 = x + ((size_t)b * LSEQ + chosen[3]) * D;
    float s[8];
#pragma unroll
    for (int j = 0; j < 8; ++j) {
        int i = i0 + j;
        s[j] = (e[0] * xr0[i] + e[1] * xr1[i] + e[2] * xr2[i] + e[3] * xr3[i]) * inv;
    }
    uint4 o;
    o.x = (uint)f2bf(s[0]) | ((uint)f2bf(s[1]) << 16);
    o.y = (uint)f2bf(s[2]) | ((uint)f2bf(s[3]) << 16);
    o.z = (uint)f2bf(s[4]) | ((uint)f2bf(s[5]) << 16);
    o.w = (uint)f2bf(s[6]) | ((uint)f2bf(s[7]) << 16);
    *(uint4*)(xbar_b + (size_t)bs * D + i0) = o;
}

// ---------------- ws = rms(ws_prev + written) (+bf16 copy) ----------------
__global__ __launch_bounds__(256) void ws_update_kernel(
    const float* __restrict__ written, const float* __restrict__ ws_prev,
    const float* __restrict__ workspace0, int first,
    const float* __restrict__ wpost, float* __restrict__ ws_out,
    ushort* __restrict__ ws_b) {
    int bs = blockIdx.x;
    int s = bs & (NSLOT - 1);
    int tid = threadIdx.x;
    int i0 = tid * 8;
    const float* prev = first ? (workspace0 + (size_t)s * D) : (ws_prev + (size_t)bs * D);
    const float* wr = written + (size_t)bs * D;
    float4 p0 = *(const float4*)(prev + i0);
    float4 p1 = *(const float4*)(prev + i0 + 4);
    float4 q0 = *(const float4*)(wr + i0);
    float4 q1 = *(const float4*)(wr + i0 + 4);
    float t[8] = {p0.x + q0.x, p0.y + q0.y, p0.z + q0.z, p0.w + q0.w,
                  p1.x + q1.x, p1.y + q1.y, p1.z + q1.z, p1.w + q1.w};
    float ss = 0.f;
#pragma unroll
    for (int j = 0; j < 8; ++j) ss += t[j] * t[j];
    ss = wave_sum(ss);
    __shared__ float sb[4];
    if ((tid & 63) == 0) sb[tid >> 6] = ss;
    __syncthreads();
    ss = sb[0] + sb[1] + sb[2] + sb[3];
    float rsq = 1.0f / sqrtf(ss * (1.0f / (float)D) + EPSV);
    float4 w0 = *(const float4*)(wpost + i0);
    float4 w1 = *(const float4*)(wpost + i0 + 4);
    float wv[8] = {w0.x, w0.y, w0.z, w0.w, w1.x, w1.y, w1.z, w1.w};
    float o[8];
#pragma unroll
    for (int j = 0; j < 8; ++j) o[j] = t[j] * rsq * wv[j];
    float4 r0 = {o[0], o[1], o[2], o[3]};
    float4 r1 = {o[4], o[5], o[6], o[7]};
    *(float4*)(ws_out + (size_t)bs * D + i0) = r0;
    *(float4*)(ws_out + (size_t)bs * D + i0 + 4) = r1;
    uint4 ob;
    ob.x = (uint)f2bf(o[0]) | ((uint)f2bf(o[1]) << 16);
    ob.y = (uint)f2bf(o[2]) | ((uint)f2bf(o[3]) << 16);
    ob.z = (uint)f2bf(o[4]) | ((uint)f2bf(o[5]) << 16);
    ob.w = (uint)f2bf(o[6]) | ((uint)f2bf(o[7]) << 16);
    *(uint4*)(ws_b + (size_t)bs * D + i0) = ob;
}

// ---------------- x = rms(x + attn_out) (+bf16 copy) ----------------
__global__ __launch_bounds__(256) void resid_rms_kernel(
    const float* __restrict__ x_src, const float* __restrict__ ao,
    const float* __restrict__ wpost, float* __restrict__ x_dst,
    ushort* __restrict__ xb) {
    int row = blockIdx.x;
    int tid = threadIdx.x;
    int i0 = tid * 8;
    const float* xr = x_src + (size_t)row * D;
    const float* ar = ao + (size_t)row * D;
    float4 p0 = *(const float4*)(xr + i0);
    float4 p1 = *(const float4*)(xr + i0 + 4);
    float4 q0 = *(const float4*)(ar + i0);
    float4 q1 = *(const float4*)(ar + i0 + 4);
    float t[8] = {p0.x + q0.x, p0.y + q0.y, p0.z + q0.z, p0.w + q0.w,
                  p1.x + q1.x, p1.y + q1.y, p1.z + q1.z, p1.w + q1.w};
    float ss = 0.f;
#pragma unroll
    for (int j = 0; j < 8; ++j) ss += t[j] * t[j];
    ss = wave_sum(ss);
    __shared__ float sb[4];
    if ((tid & 63) == 0) sb[tid >> 6] = ss;
    __syncthreads();
    ss = sb[0] + sb[1] + sb[2] + sb[3];
    float rsq = 1.0f / sqrtf(ss * (1.0f / (float)D) + EPSV);
    float4 w0 = *(const float4*)(wpost + i0);
    float4 w1 = *(const float4*)(wpost + i0 + 4);
    float wv[8] = {w0.x, w0.y, w0.z, w0.w, w1.x, w1.y, w1.z, w1.w};
    float o[8];
#pragma unroll
    for (int j = 0; j < 8; ++j) o[j] = t[j] * rsq * wv[j];
    float4 r0 = {o[0], o[1], o[2], o[3]};
    float4 r1 = {o[4], o[5], o[6], o[7]};
    *(float4*)(x_dst + (size_t)row * D + i0) = r0;
    *(float4*)(x_dst + (size_t)row * D + i0 + 4) = r1;
    uint4 ob;
    ob.x = (uint)f2bf(o[0]) | ((uint)f2bf(o[1]) << 16);
    ob.y = (uint)f2bf(o[2]) | ((uint)f2bf(o[3]) << 16);
    ob.z = (uint)f2bf(o[4]) | ((uint)f2bf(o[5]) << 16);
    ob.w = (uint)f2bf(o[6]) | ((uint)f2bf(o[7]) << 16);
    *(uint4*)(xb + (size_t)row * D + i0) = ob;
}

// ---------------- cbias[b*512+hs] = sum_d K[b,h,s,d]*bq[h*64+d] ----------------
__global__ __launch_bounds__(256) void cbias_kernel(const ushort* __restrict__ kb16,
                                                    const float* __restrict__ bq,
                                                    float* __restrict__ cb) {
    int i = blockIdx.x * 256 + threadIdx.x;   // 0..2047
    int hs = i & 511;
    int h = hs >> 4;
    const ushort* kr = kb16 + (size_t)i * 64;
    const float* bb = bq + h * 64;
    float acc = 0.f;
#pragma unroll
    for (int d = 0; d < 64; ++d)
        acc += __uint_as_float(((uint)kr[d]) << 16) * bb[d];
    cb[i] = acc;
}

// ---------------- grouped 16x64 GEMM: per (b,h): C[16x2048] = A[16x64] @ Bslice^T --
template <int TRANS>
__global__ __launch_bounds__(256) void grouped16_kernel(
    const ushort* __restrict__ Abase, const ushort* __restrict__ Bmat,
    ushort* __restrict__ Cout) {
    int blk = blockIdx.x;           // g*8 + nt   (1024 blocks)
    int g = blk >> 3;               // 0..127 = b*32+h
    int nt = blk & 7;
    int h = g & 31;
    int hoff = h * 64;
    int tid = threadIdx.x, lane = tid & 63, wv = tid >> 6;
    int j0 = nt * 256 + wv * 64;
    int rr = lane & 15, ko = lane >> 4;
    const ushort* A = Abase + (size_t)g * 16 * 64;
    bf16x8 af0 = *(const bf16x8*)(A + rr * 64 + ko * 8);
    bf16x8 af1 = *(const bf16x8*)(A + rr * 64 + 32 + ko * 8);
    f32x4 acc[4];
    f32x4 zero = {0.f, 0.f, 0.f, 0.f};
#pragma unroll
    for (int nf = 0; nf < 4; ++nf) acc[nf] = zero;
#pragma unroll
    for (int nf = 0; nf < 4; ++nf) {
        int j = j0 + nf * 16 + rr;
        bf16x8 b0 = *(const bf16x8*)(Bmat + (size_t)j * 2048 + hoff + ko * 8);
        bf16x8 b1 = *(const bf16x8*)(Bmat + (size_t)j * 2048 + hoff + 32 + ko * 8);
        acc[nf] = __builtin_amdgcn_mfma_f32_16x16x32_bf16(af0, b0, acc[nf], 0, 0, 0);
        acc[nf] = __builtin_amdgcn_mfma_f32_16x16x32_bf16(af1, b1, acc[nf], 0, 0, 0);
    }
#pragma unroll
    for (int nf = 0; nf < 4; ++nf)
#pragma unroll
        for (int r = 0; r < 4; ++r) {
            int s = ko * 4 + r;
            int j = j0 + nf * 16 + rr;
            ushort v = f2bf(acc[nf][r]);
            if (TRANS) Cout[(size_t)j * 2048 + g * 16 + s] = v;
            else       Cout[(size_t)(g * 16 + s) * 2048 + j] = v;
        }
}

// ---------------- attn softmax: A_att = softmax_s((qlog0+qlog1+cbias)*0.125) ------
__global__ __launch_bounds__(256) void attn_sm_kernel(
    const float* __restrict__ qlog, const float* __restrict__ cb,
    ushort* __restrict__ aatt) {
    int blk = blockIdx.x;               // 1024 blocks x 8 rows
    int tid = threadIdx.x;
    int l = blk * 8 + (tid >> 5);
    int b = l >> 11;
    int h = tid & 31;
    const float* q0 = qlog + (size_t)l * 512 + h * 16;
    const float* q1 = q0 + (size_t)BL * 512;
    const float* c = cb + b * 512 + h * 16;
    float p[16];
#pragma unroll
    for (int i = 0; i < 16; i += 4) {
        float4 v0 = *(const float4*)(q0 + i);
        float4 v1 = *(const float4*)(q1 + i);
        float4 cc = *(const float4*)(c + i);
        p[i]     = v0.x + v1.x + cc.x;
        p[i + 1] = v0.y + v1.y + cc.y;
        p[i + 2] = v0.z + v1.z + cc.z;
        p[i + 3] = v0.w + v1.w + cc.w;
    }
    float mx = p[0];
#pragma unroll
    for (int s = 1; s < 16; ++s) mx = fmaxf(mx, p[s]);
    float den = 0.f;
#pragma unroll
    for (int s = 0; s < 16; ++s) { p[s] = __expf((p[s] - mx) * 0.125f); den += p[s]; }
    float inv = 1.0f / den;
    uint4 o[2];
    uint* ow = (uint*)o;
#pragma unroll
    for (int i = 0; i < 8; ++i)
        ow[i] = (uint)f2bf(p[2 * i] * inv) | ((uint)f2bf(p[2 * i + 1] * inv) << 16);
    ushort* dst = aatt + (size_t)l * 512 + h * 16;
    *(uint4*)dst = o[0];
    *(uint4*)(dst + 8) = o[1];
}

// ---------------- bf16 MFMA GEMM: C[m,n] = sum_k A[m,k]*Bw[n,k] + bias[n] ----------
// bOff: per-batch B offset (batch = row-tile>>11); bStride/aStride: row strides.
// blockIdx.z = K-split slice: A += z*zA, Bw += z*zB, C += z*zC (elements).
// kv mode (kvk!=null) writes per-head bf16 K/V.
template <int BM>
__global__ __launch_bounds__(256) void gemm_bt(
    const ushort* __restrict__ A, const ushort* __restrict__ Bw,
    const float* __restrict__ bias, float* __restrict__ C,
    int M, int N, int K, ushort* __restrict__ kvk, ushort* __restrict__ kvv,
    size_t bOff, int bStride, int aStride, int zA, int zB, size_t zC) {
    constexpr int BN = 128, BK = 32;
    constexpr int MF = BM / 32;
    constexpr int APASS = (BM * BK / 8) / 256;
    __shared__ short lds[2][(BM + BN) * BK];
    int tid = threadIdx.x;
    int lane = tid & 63, w = tid >> 6;
    int wr = w >> 1, wc = w & 1;
    int tn = blockIdx.x * BN;
    int tm = blockIdx.y * BM;
    int ksl = blockIdx.z;
    A += (size_t)ksl * zA;
    Bw += (size_t)ksl * zB + (size_t)(tm >> 11) * bOff;
    C += (size_t)ksl * zC;
    f32x4 acc[MF][4];
    f32x4 zero = {0.f, 0.f, 0.f, 0.f};
#pragma unroll
    for (int m = 0; m < MF; ++m)
#pragma unroll
        for (int n = 0; n < 4; ++n) acc[m][n] = zero;
    int NT = K / BK;

    auto stage = [&](int buf, int t) {
        int kt = t * BK;
#pragma unroll
        for (int p = 0; p < APASS; ++p) {
            int cb = p * 256 + w * 64;
            int c = cb + lane;
            int r = c >> 2;
            int k8 = (c & 3) * 8;
            int gr = tm + r;
            if (gr >= M) gr = M - 1;
            gl_lds16(A + (size_t)gr * aStride + kt + k8, (void*)&lds[buf][cb * 8]);
        }
#pragma unroll
        for (int p = 0; p < 2; ++p) {
            int cb = p * 256 + w * 64;
            int c = cb + lane;
            int r = c >> 2;
            int k8 = (c & 3) * 8;
            gl_lds16(Bw + (size_t)(tn + r) * bStride + kt + k8,
                     (void*)&lds[buf][BM * BK + cb * 8]);
        }
    };
    stage(0, 0);
    for (int t = 0; t < NT; ++t) {
        __syncthreads();
        if (t + 1 < NT) stage((t + 1) & 1, t + 1);
        const short* Ab = &lds[t & 1][0];
        const short* Bb = &lds[t & 1][BM * BK];
        int ko = (lane >> 4) * 8;
        int rr = lane & 15;
        bf16x8 af[MF], bfr[4];
#pragma unroll
        for (int m = 0; m < MF; ++m)
            af[m] = *(const bf16x8*)&Ab[(wr * (MF * 16) + m * 16 + rr) * BK + ko];
#pragma unroll
        for (int n = 0; n < 4; ++n)
            bfr[n] = *(const bf16x8*)&Bb[(wc * 64 + n * 16 + rr) * BK + ko];
#pragma unroll
        for (int m = 0; m < MF; ++m)
#pragma unroll
            for (int n = 0; n < 4; ++n)
                acc[m][n] = __builtin_amdgcn_mfma_f32_16x16x32_bf16(af[m], bfr[n],
                                                                    acc[m][n], 0, 0, 0);
    }
#pragma unroll
    for (int m = 0; m < MF; ++m) {
#pragma unroll
        for (int n = 0; n < 4; ++n) {
            int col = tn + wc * 64 + n * 16 + (lane & 15);
            float bsv = bias ? bias[col] : 0.f;
#pragma unroll
            for (int r = 0; r < 4; ++r) {
                int rowi = tm + wr * (MF * 16) + m * 16 + (lane >> 4) * 4 + r;
                if (rowi >= M) continue;
                float v = acc[m][n][r] + bsv;
                if (kvk) {
                    // kv mode: row = b*16+s, col<2048 -> K head h, else V
                    int b = rowi >> 4, s = rowi & 15;
                    int c2 = (col < 2048) ? col : col - 2048;
                    int h = c2 >> 6, d = c2 & 63;
                    size_t dst = (((size_t)(b * NHEAD + h)) * NSLOT + s) * HDIM + d;
                    if (col < 2048) kvk[dst] = f2bf(v);
                    else            kvv[dst] = f2bf(v);
                } else {
                    C[(size_t)rowi * N + col] = v;
                }
            }
        }
    }
}

extern "C" void kernel_launch(void* const* d_in, const int* in_sizes, int n_in,
                              void* d_out, int out_size, void* d_ws, size_t ws_size,
                              hipStream_t stream) {
    const float* x_in       = (const float*)d_in[0];
    const float* workspace  = (const float*)d_in[1];
    const float* compete_w  = (const float*)d_in[2];
    const float* compete_b  = (const float*)d_in[3];
    const float* write_w    = (const float*)d_in[4];
    const float* write_b    = (const float*)d_in[5];
    const float* in_proj_w  = (const float*)d_in[6];
    const float* in_proj_b  = (const float*)d_in[7];
    const float* out_proj_w = (const float*)d_in[8];
    const float* out_proj_b = (const float*)d_in[9];
    const float* norm_pre_w  = (const float*)d_in[12];
    const float* norm_post_w = (const float*)d_in[13];
    float* xout = (float*)d_out;

    char* base = (char*)d_ws;
    size_t off = 0;
    auto alloc = [&](size_t bytes) {
        void* p = base + off;
        off += (bytes + 255) & ~(size_t)255;
        return p;
    };
    ushort* xb      = (ushort*)alloc((size_t)BL * D * 2);
    float*  qbuf    = (float*) alloc((size_t)BL * D * 4);     // x_b (f32)
    float*  logits  = (float*) alloc((size_t)BATCH * NSLOT * LSEQ * 4);
    ushort* xbar    = (ushort*)alloc((size_t)BATCH * NSLOT * D * 2);
    float*  written = (float*) alloc((size_t)BATCH * NSLOT * D * 4);
    float*  wsbuf   = (float*) alloc((size_t)BATCH * NSLOT * D * 4);
    ushort* wsb     = (ushort*)alloc((size_t)BATCH * NSLOT * D * 2);
    ushort* ipb     = (ushort*)alloc((size_t)3 * D * D * 2);
    ushort* wob     = (ushort*)alloc((size_t)D * D * 2);
    ushort* wwb     = (ushort*)alloc((size_t)D * D * 2);
    ushort* wqt     = (ushort*)alloc((size_t)D * D * 2);      // Wq^T bf16
    ushort* kb16    = (ushort*)alloc((size_t)BATCH * NHEAD * NSLOT * HDIM * 2);
    ushort* vb16    = (ushort*)alloc((size_t)BATCH * NHEAD * NSLOT * HDIM * 2);
    ushort* ktil    = (ushort*)alloc((size_t)BATCH * 512 * D * 2);   // K~ rows b*512+hs
    ushort* wtilT   = (ushort*)alloc((size_t)D * BATCH * 512 * 2);   // W~^T rows j
    float*  qlog    = (float*) alloc((size_t)2 * BL * 512 * 4);      // 2 K-split planes
    ushort* aatt    = (ushort*)alloc((size_t)BL * 512 * 2);
    float*  cbias   = (float*) alloc((size_t)BATCH * 512 * 4);
    (void)ws_size; (void)in_sizes; (void)n_in; (void)out_size;

    conv_bf16_kernel<<<2048, 256, 0, stream>>>((const float4*)in_proj_w, ipb, 3 * D * D / 4);
    conv_bf16_kernel<<<2048, 256, 0, stream>>>((const float4*)out_proj_w, wob, D * D / 4);
    conv_bf16_kernel<<<2048, 256, 0, stream>>>((const float4*)write_w, wwb, D * D / 4);
    conv_bf16_kernel<<<2048, 256, 0, stream>>>((const float4*)x_in, xb, BL * D / 4);
    transpose_bf16_kernel<<<1024, 256, 0, stream>>>(ipb, wqt);   // Wq^T (q rows 0..D)

    for (int it = 0; it < 2; ++it) {
        const float* xs = it ? (const float*)xout : x_in;
        logits_kernel<<<BL / 4, 256, 0, stream>>>(xs, compete_w, compete_b, norm_pre_w,
                                                  logits);
        topk_xbar_kernel<<<BATCH * NSLOT, 256, 0, stream>>>(logits, xs, xbar);
        gemm_bt<64><<<dim3(D / 128, 1), 256, 0, stream>>>(xbar, wwb, write_b, written,
                                                          BATCH * NSLOT, D, D,
                                                          (ushort*)nullptr, (ushort*)nullptr,
                                                          0, D, D, 0, 0, 0);
        ws_update_kernel<<<BATCH * NSLOT, 256, 0, stream>>>(written, wsbuf, workspace,
                                                            it == 0 ? 1 : 0, norm_post_w,
                                                            wsbuf, wsb);
        gemm_bt<64><<<dim3(2 * D / 128, 1), 256, 0, stream>>>(wsb, ipb + (size_t)D * D,
                                                              in_proj_b + D, (float*)nullptr,
                                                              BATCH * NSLOT, 2 * D, D,
                                                              kb16, vb16, 0, D, D, 0, 0, 0);
        cbias_kernel<<<8, 256, 0, stream>>>(kb16, in_proj_b, cbias);
        grouped16_kernel<0><<<1024, 256, 0, stream>>>(kb16, wqt, ktil);
        grouped16_kernel<1><<<1024, 256, 0, stream>>>(vb16, wob, wtilT);
        // qlog[z][l, hs] = xb[l, zK:zK+1024] . K~[b,hs, zK:zK+1024]  (split-K=2)
        gemm_bt<64><<<dim3(512 / 128, BL / 64, 2), 256, 0, stream>>>(
            xb, ktil, (const float*)nullptr, qlog, BL, 512, D / 2,
            (ushort*)nullptr, (ushort*)nullptr,
            (size_t)512 * D, D, D, D / 2, D / 2, (size_t)BL * 512);
        attn_sm_kernel<<<BL / 8, 256, 0, stream>>>(qlog, cbias, aatt);
        // x_b[l, j] = sum_hs aatt[l,hs] * W~T[j, b*512+hs] + out_proj_b[j]
        gemm_bt<128><<<dim3(D / 128, BL / 128), 256, 0, stream>>>(
            aatt, wtilT, out_proj_b, qbuf, BL, D, 512,
            (ushort*)nullptr, (ushort*)nullptr, (size_t)512, D, 512, 0, 0, 0);
        resid_rms_kernel<<<BL, 256, 0, stream>>>(xs, qbuf, norm_post_w, xout, xb);
    }
}

// Round 14
// 548.380 us; speedup vs baseline: 1.5385x; 1.0935x over previous
//
#include <hip/hip_runtime.h>
#include <stdint.h>

#define D 2048
#define LSEQ 2048
#define BATCH 4
#define BL (BATCH * LSEQ)   // 8192 rows
#define NSLOT 16
#define NHEAD 32
#define HDIM 64
#define EPSV 1e-6f

typedef __attribute__((ext_vector_type(8))) short bf16x8;
typedef __attribute__((ext_vector_type(4))) float f32x4;

static __device__ __forceinline__ ushort f2bf(float f) {
    uint32_t u = __float_as_uint(f);
    u += 0x7fffu + ((u >> 16) & 1u);   // RNE
    return (ushort)(u >> 16);
}

static __device__ __forceinline__ float wave_sum(float v) {
#pragma unroll
    for (int off = 32; off > 0; off >>= 1) v += __shfl_xor(v, off, 64);
    return v;
}

static __device__ __forceinline__ void gl_lds16(const void* g, void* l) {
    __builtin_amdgcn_global_load_lds(
        (__attribute__((address_space(1))) uint32_t*)(uintptr_t)g,
        (__attribute__((address_space(3))) uint32_t*)(uint32_t)(uintptr_t)l,
        16, 0, 0);
}

// ---------------- weight convert f32 -> bf16 ----------------
__global__ __launch_bounds__(256) void conv_bf16_kernel(const float4* __restrict__ src,
                                                        ushort* __restrict__ dst, int n4) {
    int i = blockIdx.x * 256 + threadIdx.x;
    int stride = gridDim.x * 256;
    for (; i < n4; i += stride) {
        float4 v = src[i];
        uint2 o;
        o.x = (uint)f2bf(v.x) | ((uint)f2bf(v.y) << 16);
        o.y = (uint)f2bf(v.z) | ((uint)f2bf(v.w) << 16);
        *(uint2*)(dst + (size_t)i * 4) = o;
    }
}

// ---------------- 2048x2048 bf16 transpose (once, for Wq^T) ----------------
__global__ __launch_bounds__(256) void transpose_bf16_kernel(const ushort* __restrict__ src,
                                                             ushort* __restrict__ dst) {
    __shared__ ushort t[64][72];
    int bx = blockIdx.x & 31, by = blockIdx.x >> 5;
    int r0 = by * 64, c0 = bx * 64;
    int tid = threadIdx.x;
    int lr = tid >> 3;
    int lc = (tid & 7) * 8;
#pragma unroll
    for (int p = 0; p < 2; ++p) {
        int rr = p * 32 + lr;
        bf16x8 v = *(const bf16x8*)(src + (size_t)(r0 + rr) * 2048 + c0 + lc);
#pragma unroll
        for (int j = 0; j < 8; ++j) t[lc + j][rr] = (ushort)v[j];
    }
    __syncthreads();
#pragma unroll
    for (int p = 0; p < 2; ++p) {
        int rr = p * 32 + lr;
        *(bf16x8*)(dst + (size_t)(c0 + rr) * 2048 + r0 + lc) = *(const bf16x8*)&t[rr][lc];
    }
}

// ---------------- logits v4: 4 rows/block, BIT-EXACT to the R4-passing kernel ----
// DO NOT change any arithmetic here: logits bits feed top-k (an order-statistic
// discontinuity); R5 failed from a 1e-7-level summation-order change.
__global__ __launch_bounds__(256) void logits_kernel(
    const float* __restrict__ x, const float* __restrict__ cw,
    const float* __restrict__ cb, const float* __restrict__ wpre,
    float* __restrict__ logits_t) {
    int blk = blockIdx.x;              // 2048 blocks, 4 rows each
    int b = blk >> 9;                  // 512 blocks per batch
    int l0 = (blk & 511) << 2;
    int tid = threadIdx.x;
    int i0 = tid * 8;
    float4 w0 = *(const float4*)(wpre + i0);
    float4 w1 = *(const float4*)(wpre + i0 + 4);
    float wv[8] = {w0.x, w0.y, w0.z, w0.w, w1.x, w1.y, w1.z, w1.w};
    float xw[4][8];
    float ss[4];
#pragma unroll
    for (int r = 0; r < 4; ++r) {
        const float* xr = x + ((size_t)(b * LSEQ + l0 + r)) * D;
        float4 a0 = *(const float4*)(xr + i0);
        float4 a1 = *(const float4*)(xr + i0 + 4);
        float xv[8] = {a0.x, a0.y, a0.z, a0.w, a1.x, a1.y, a1.z, a1.w};
        float s0 = 0.f;
#pragma unroll
        for (int j = 0; j < 8; ++j) { s0 += xv[j] * xv[j]; xw[r][j] = xv[j] * wv[j]; }
        ss[r] = s0;
    }
    float acc[NSLOT][4];
#pragma unroll
    for (int s = 0; s < NSLOT; ++s) {
        const float* cwr = cw + (size_t)s * D + i0;
        float4 c0 = *(const float4*)(cwr);
        float4 c1 = *(const float4*)(cwr + 4);
#pragma unroll
        for (int r = 0; r < 4; ++r)
            acc[s][r] = xw[r][0] * c0.x + xw[r][1] * c0.y + xw[r][2] * c0.z + xw[r][3] * c0.w +
                        xw[r][4] * c1.x + xw[r][5] * c1.y + xw[r][6] * c1.z + xw[r][7] * c1.w;
    }
#pragma unroll
    for (int r = 0; r < 4; ++r) ss[r] = wave_sum(ss[r]);
#pragma unroll
    for (int s = 0; s < NSLOT; ++s)
#pragma unroll
        for (int r = 0; r < 4; ++r) acc[s][r] = wave_sum(acc[s][r]);
    __shared__ float red[4][NSLOT][4];
    __shared__ float redss[4][4];
    int lane = tid & 63, w = tid >> 6;
    if (lane == 0) {
#pragma unroll
        for (int r = 0; r < 4; ++r) redss[w][r] = ss[r];
#pragma unroll
        for (int s = 0; s < NSLOT; ++s)
#pragma unroll
            for (int r = 0; r < 4; ++r) red[w][s][r] = acc[s][r];
    }
    __syncthreads();
    if (tid < 64) {
        int s = tid >> 2, r = tid & 3;
        float tot = red[0][s][r] + red[1][s][r] + red[2][s][r] + red[3][s][r];
        float s2 = redss[0][r] + redss[1][r] + redss[2][r] + redss[3][r];
        float rsq = 1.0f / sqrtf(s2 * (1.0f / (float)D) + EPSV);
        logits_t[((size_t)(b * NSLOT + s)) * LSEQ + l0 + r] = tot * rsq + cb[s];
    }
}

// ---------------- top-4 + softmax + weighted row gather (xbar, bf16) ----------------
__global__ __launch_bounds__(256) void topk_xbar_kernel(
    const float* __restrict__ logits_t, const float* __restrict__ x,
    ushort* __restrict__ xbar_b) {
    int bs = blockIdx.x;
    int b = bs >> 4;
    const float* lr = logits_t + (size_t)bs * LSEQ;
    int tid = threadIdx.x, lane = tid & 63, w = tid >> 6;
    __shared__ float rv[4];
    __shared__ int ri[4];
    __shared__ float selv[4];
    __shared__ int seli[4];
    int i0 = tid * 8;
    float myv[8];
#pragma unroll
    for (int j = 0; j < 8; ++j) myv[j] = lr[i0 + j];
    int chosen[4];
    for (int p = 0; p < 4; ++p) {
        float bv = -3.4e38f;
        int bi = 0x7fffffff;
#pragma unroll
        for (int j = 0; j < 8; ++j) {
            int i = i0 + j;
            bool skip = false;
            for (int q = 0; q < p; ++q) skip = skip || (i == chosen[q]);
            float v = myv[j];
            if (!skip && (v > bv || (v == bv && i < bi))) { bv = v; bi = i; }
        }
#pragma unroll
        for (int off = 1; off < 64; off <<= 1) {
            float ov = __shfl_xor(bv, off, 64);
            int oi = __shfl_xor(bi, off, 64);
            if (ov > bv || (ov == bv && oi < bi)) { bv = ov; bi = oi; }
        }
        if (lane == 0) { rv[w] = bv; ri[w] = bi; }
        __syncthreads();
        if (tid == 0) {
            float fv = rv[0];
            int fi = ri[0];
            for (int q = 1; q < 4; ++q)
                if (rv[q] > fv || (rv[q] == fv && ri[q] < fi)) { fv = rv[q]; fi = ri[q]; }
            selv[p] = fv;
            seli[p] = fi;
        }
        __syncthreads();
        chosen[p] = seli[p];
    }
    float vals[4];
#pragma unroll
    for (int p = 0; p < 4; ++p) vals[p] = selv[p];
    float mx = vals[0];   // first pick is the max
    float e[4], den = 0.f;
#pragma unroll
    for (int p = 0; p < 4; ++p) { e[p] = expf(vals[p] - mx); den += e[p]; }
    float inv = 1.0f / den;
    const float* xr0 = x + ((size_t)b * LSEQ + chosen[0]) * D;
    const float* xr1 = x + ((size_t)b * LSEQ + chosen[1]) * D;
    const float* xr2 = x + ((size_t)b * LSEQ + chosen[2]) * D;
    const float* xr3 = x + ((size_t)b * LSEQ + chosen[3]) * D;
    float s[8];
#pragma unroll
    for (int j = 0; j < 8; ++j) {
        int i = i0 + j;
        s[j] = (e[0] * xr0[i] + e[1] * xr1[i] + e[2] * xr2[i] + e[3] * xr3[i]) * inv;
    }
    uint4 o;
    o.x = (uint)f2bf(s[0]) | ((uint)f2bf(s[1]) << 16);
    o.y = (uint)f2bf(s[2]) | ((uint)f2bf(s[3]) << 16);
    o.z = (uint)f2bf(s[4]) | ((uint)f2bf(s[5]) << 16);
    o.w = (uint)f2bf(s[6]) | ((uint)f2bf(s[7]) << 16);
    *(uint4*)(xbar_b + (size_t)bs * D + i0) = o;
}

// ---------------- ws = rms(ws_prev + written) (+bf16 copy) ----------------
__global__ __launch_bounds__(256) void ws_update_kernel(
    const float* __restrict__ written, const float* __restrict__ ws_prev,
    const float* __restrict__ workspace0, int first,
    const float* __restrict__ wpost, float* __restrict__ ws_out,
    ushort* __restrict__ ws_b) {
    int bs = blockIdx.x;
    int s = bs & (NSLOT - 1);
    int tid = threadIdx.x;
    int i0 = tid * 8;
    const float* prev = first ? (workspace0 + (size_t)s * D) : (ws_prev + (size_t)bs * D);
    const float* wr = written + (size_t)bs * D;
    float4 p0 = *(const float4*)(prev + i0);
    float4 p1 = *(const float4*)(prev + i0 + 4);
    float4 q0 = *(const float4*)(wr + i0);
    float4 q1 = *(const float4*)(wr + i0 + 4);
    float t[8] = {p0.x + q0.x, p0.y + q0.y, p0.z + q0.z, p0.w + q0.w,
                  p1.x + q1.x, p1.y + q1.y, p1.z + q1.z, p1.w + q1.w};
    float ss = 0.f;
#pragma unroll
    for (int j = 0; j < 8; ++j) ss += t[j] * t[j];
    ss = wave_sum(ss);
    __shared__ float sb[4];
    if ((tid & 63) == 0) sb[tid >> 6] = ss;
    __syncthreads();
    ss = sb[0] + sb[1] + sb[2] + sb[3];
    float rsq = 1.0f / sqrtf(ss * (1.0f / (float)D) + EPSV);
    float4 w0 = *(const float4*)(wpost + i0);
    float4 w1 = *(const float4*)(wpost + i0 + 4);
    float wv[8] = {w0.x, w0.y, w0.z, w0.w, w1.x, w1.y, w1.z, w1.w};
    float o[8];
#pragma unroll
    for (int j = 0; j < 8; ++j) o[j] = t[j] * rsq * wv[j];
    float4 r0 = {o[0], o[1], o[2], o[3]};
    float4 r1 = {o[4], o[5], o[6], o[7]};
    *(float4*)(ws_out + (size_t)bs * D + i0) = r0;
    *(float4*)(ws_out + (size_t)bs * D + i0 + 4) = r1;
    uint4 ob;
    ob.x = (uint)f2bf(o[0]) | ((uint)f2bf(o[1]) << 16);
    ob.y = (uint)f2bf(o[2]) | ((uint)f2bf(o[3]) << 16);
    ob.z = (uint)f2bf(o[4]) | ((uint)f2bf(o[5]) << 16);
    ob.w = (uint)f2bf(o[6]) | ((uint)f2bf(o[7]) << 16);
    *(uint4*)(ws_b + (size_t)bs * D + i0) = ob;
}

// ---------------- x = rms(x + attn_out) (+bf16 copy) ----------------
__global__ __launch_bounds__(256) void resid_rms_kernel(
    const float* __restrict__ x_src, const float* __restrict__ ao,
    const float* __restrict__ wpost, float* __restrict__ x_dst,
    ushort* __restrict__ xb) {
    int row = blockIdx.x;
    int tid = threadIdx.x;
    int i0 = tid * 8;
    const float* xr = x_src + (size_t)row * D;
    const float* ar = ao + (size_t)row * D;
    float4 p0 = *(const float4*)(xr + i0);
    float4 p1 = *(const float4*)(xr + i0 + 4);
    float4 q0 = *(const float4*)(ar + i0);
    float4 q1 = *(const float4*)(ar + i0 + 4);
    float t[8] = {p0.x + q0.x, p0.y + q0.y, p0.z + q0.z, p0.w + q0.w,
                  p1.x + q1.x, p1.y + q1.y, p1.z + q1.z, p1.w + q1.w};
    float ss = 0.f;
#pragma unroll
    for (int j = 0; j < 8; ++j) ss += t[j] * t[j];
    ss = wave_sum(ss);
    __shared__ float sb[4];
    if ((tid & 63) == 0) sb[tid >> 6] = ss;
    __syncthreads();
    ss = sb[0] + sb[1] + sb[2] + sb[3];
    float rsq = 1.0f / sqrtf(ss * (1.0f / (float)D) + EPSV);
    float4 w0 = *(const float4*)(wpost + i0);
    float4 w1 = *(const float4*)(wpost + i0 + 4);
    float wv[8] = {w0.x, w0.y, w0.z, w0.w, w1.x, w1.y, w1.z, w1.w};
    float o[8];
#pragma unroll
    for (int j = 0; j < 8; ++j) o[j] = t[j] * rsq * wv[j];
    float4 r0 = {o[0], o[1], o[2], o[3]};
    float4 r1 = {o[4], o[5], o[6], o[7]};
    *(float4*)(x_dst + (size_t)row * D + i0) = r0;
    *(float4*)(x_dst + (size_t)row * D + i0 + 4) = r1;
    uint4 ob;
    ob.x = (uint)f2bf(o[0]) | ((uint)f2bf(o[1]) << 16);
    ob.y = (uint)f2bf(o[2]) | ((uint)f2bf(o[3]) << 16);
    ob.z = (uint)f2bf(o[4]) | ((uint)f2bf(o[5]) << 16);
    ob.w = (uint)f2bf(o[6]) | ((uint)f2bf(o[7]) << 16);
    *(uint4*)(xb + (size_t)row * D + i0) = ob;
}

// ---------------- cbias[b*512+hs] = sum_d K[b,h,s,d]*bq[h*64+d] ----------------
__global__ __launch_bounds__(256) void cbias_kernel(const ushort* __restrict__ kb16,
                                                    const float* __restrict__ bq,
                                                    float* __restrict__ cb) {
    int i = blockIdx.x * 256 + threadIdx.x;   // 0..2047
    int hs = i & 511;
    int h = hs >> 4;
    const ushort* kr = kb16 + (size_t)i * 64;
    const float* bb = bq + h * 64;
    float acc = 0.f;
#pragma unroll
    for (int d = 0; d < 64; ++d)
        acc += __uint_as_float(((uint)kr[d]) << 16) * bb[d];
    cb[i] = acc;
}

// ---------------- grouped 16x64 GEMM: per (b,h): C[16x2048] = A[16x64] @ Bslice^T --
template <int TRANS>
__global__ __launch_bounds__(256) void grouped16_kernel(
    const ushort* __restrict__ Abase, const ushort* __restrict__ Bmat,
    ushort* __restrict__ Cout) {
    int blk = blockIdx.x;           // g*8 + nt   (1024 blocks)
    int g = blk >> 3;               // 0..127 = b*32+h
    int nt = blk & 7;
    int h = g & 31;
    int hoff = h * 64;
    int tid = threadIdx.x, lane = tid & 63, wv = tid >> 6;
    int j0 = nt * 256 + wv * 64;
    int rr = lane & 15, ko = lane >> 4;
    const ushort* A = Abase + (size_t)g * 16 * 64;
    bf16x8 af0 = *(const bf16x8*)(A + rr * 64 + ko * 8);
    bf16x8 af1 = *(const bf16x8*)(A + rr * 64 + 32 + ko * 8);
    f32x4 acc[4];
    f32x4 zero = {0.f, 0.f, 0.f, 0.f};
#pragma unroll
    for (int nf = 0; nf < 4; ++nf) acc[nf] = zero;
#pragma unroll
    for (int nf = 0; nf < 4; ++nf) {
        int j = j0 + nf * 16 + rr;
        bf16x8 b0 = *(const bf16x8*)(Bmat + (size_t)j * 2048 + hoff + ko * 8);
        bf16x8 b1 = *(const bf16x8*)(Bmat + (size_t)j * 2048 + hoff + 32 + ko * 8);
        acc[nf] = __builtin_amdgcn_mfma_f32_16x16x32_bf16(af0, b0, acc[nf], 0, 0, 0);
        acc[nf] = __builtin_amdgcn_mfma_f32_16x16x32_bf16(af1, b1, acc[nf], 0, 0, 0);
    }
#pragma unroll
    for (int nf = 0; nf < 4; ++nf)
#pragma unroll
        for (int r = 0; r < 4; ++r) {
            int s = ko * 4 + r;
            int j = j0 + nf * 16 + rr;
            ushort v = f2bf(acc[nf][r]);
            if (TRANS) Cout[(size_t)j * 2048 + g * 16 + s] = v;
            else       Cout[(size_t)(g * 16 + s) * 2048 + j] = v;
        }
}

// ---------------- attn softmax: A_att = softmax_s((qlog0+qlog1+cbias)*0.125) ------
__global__ __launch_bounds__(256) void attn_sm_kernel(
    const float* __restrict__ qlog, const float* __restrict__ cb,
    ushort* __restrict__ aatt) {
    int blk = blockIdx.x;               // 1024 blocks x 8 rows
    int tid = threadIdx.x;
    int l = blk * 8 + (tid >> 5);
    int b = l >> 11;
    int h = tid & 31;
    const float* q0 = qlog + (size_t)l * 512 + h * 16;
    const float* q1 = q0 + (size_t)BL * 512;
    const float* c = cb + b * 512 + h * 16;
    float p[16];
#pragma unroll
    for (int i = 0; i < 16; i += 4) {
        float4 v0 = *(const float4*)(q0 + i);
        float4 v1 = *(const float4*)(q1 + i);
        float4 cc = *(const float4*)(c + i);
        p[i]     = v0.x + v1.x + cc.x;
        p[i + 1] = v0.y + v1.y + cc.y;
        p[i + 2] = v0.z + v1.z + cc.z;
        p[i + 3] = v0.w + v1.w + cc.w;
    }
    float mx = p[0];
#pragma unroll
    for (int s = 1; s < 16; ++s) mx = fmaxf(mx, p[s]);
    float den = 0.f;
#pragma unroll
    for (int s = 0; s < 16; ++s) { p[s] = __expf((p[s] - mx) * 0.125f); den += p[s]; }
    float inv = 1.0f / den;
    uint4 o[2];
    uint* ow = (uint*)o;
#pragma unroll
    for (int i = 0; i < 8; ++i)
        ow[i] = (uint)f2bf(p[2 * i] * inv) | ((uint)f2bf(p[2 * i + 1] * inv) << 16);
    ushort* dst = aatt + (size_t)l * 512 + h * 16;
    *(uint4*)dst = o[0];
    *(uint4*)(dst + 8) = o[1];
}

// ---------------- tiny-M GEMM: one wave per 16x16 output tile, no LDS/barriers ----
// Same K-order as gemm_bt (t ascending, one mfma_16x16x32 per 32-K step) and the
// same epilogue -> bit-identical outputs. A (M=64 rows) and B are L2-resident;
// 512-1024 independent waves give the latency hiding the 16-block version lacked.
// KVMODE=1: N=4096; col<2048 -> K head scatter, else V (same as gemm_bt kv mode).
template <int KVMODE>
__global__ __launch_bounds__(256) void gemm_tiny(
    const ushort* __restrict__ A, const ushort* __restrict__ Bw,
    const float* __restrict__ bias, float* __restrict__ C,
    int M, int N, int K, ushort* __restrict__ kvk, ushort* __restrict__ kvv) {
    int gw = (blockIdx.x * 256 + threadIdx.x) >> 6;
    int lane = threadIdx.x & 63;
    int ntiles = N >> 4;
    int nt = gw % ntiles, mt = gw / ntiles;
    int rr = lane & 15, ko = lane >> 4;
    const ushort* Ar = A + (size_t)(mt * 16 + rr) * K;
    const ushort* Br = Bw + (size_t)(nt * 16 + rr) * K;
    f32x4 acc = {0.f, 0.f, 0.f, 0.f};
    int NT = K / 32;
#pragma unroll 8
    for (int t = 0; t < NT; ++t) {
        bf16x8 af = *(const bf16x8*)(Ar + t * 32 + ko * 8);
        bf16x8 bf = *(const bf16x8*)(Br + t * 32 + ko * 8);
        acc = __builtin_amdgcn_mfma_f32_16x16x32_bf16(af, bf, acc, 0, 0, 0);
    }
    int col = nt * 16 + rr;
    float bsv = bias ? bias[col] : 0.f;
#pragma unroll
    for (int r = 0; r < 4; ++r) {
        int rowi = mt * 16 + ko * 4 + r;
        float v = acc[r] + bsv;
        if (KVMODE) {
            int b = rowi >> 4, s = rowi & 15;
            int c2 = (col < 2048) ? col : col - 2048;
            int h = c2 >> 6, d = c2 & 63;
            size_t dst = (((size_t)(b * NHEAD + h)) * NSLOT + s) * HDIM + d;
            if (col < 2048) kvk[dst] = f2bf(v);
            else            kvv[dst] = f2bf(v);
        } else {
            C[(size_t)rowi * N + col] = v;
        }
    }
}

// ---------------- bf16 MFMA GEMM: C[m,n] = sum_k A[m,k]*Bw[n,k] + bias[n] ----------
// bOff: per-batch B offset (batch = row-tile>>11); bStride/aStride: row strides.
// blockIdx.z = K-split slice: A += z*zA, Bw += z*zB, C += z*zC (elements).
template <int BM>
__global__ __launch_bounds__(256) void gemm_bt(
    const ushort* __restrict__ A, const ushort* __restrict__ Bw,
    const float* __restrict__ bias, float* __restrict__ C,
    int M, int N, int K, size_t bOff, int bStride, int aStride,
    int zA, int zB, size_t zC) {
    constexpr int BN = 128, BK = 32;
    constexpr int MF = BM / 32;
    constexpr int APASS = (BM * BK / 8) / 256;
    __shared__ short lds[2][(BM + BN) * BK];
    int tid = threadIdx.x;
    int lane = tid & 63, w = tid >> 6;
    int wr = w >> 1, wc = w & 1;
    int tn = blockIdx.x * BN;
    int tm = blockIdx.y * BM;
    int ksl = blockIdx.z;
    A += (size_t)ksl * zA;
    Bw += (size_t)ksl * zB + (size_t)(tm >> 11) * bOff;
    C += (size_t)ksl * zC;
    f32x4 acc[MF][4];
    f32x4 zero = {0.f, 0.f, 0.f, 0.f};
#pragma unroll
    for (int m = 0; m < MF; ++m)
#pragma unroll
        for (int n = 0; n < 4; ++n) acc[m][n] = zero;
    int NT = K / BK;

    auto stage = [&](int buf, int t) {
        int kt = t * BK;
#pragma unroll
        for (int p = 0; p < APASS; ++p) {
            int cb = p * 256 + w * 64;
            int c = cb + lane;
            int r = c >> 2;
            int k8 = (c & 3) * 8;
            int gr = tm + r;
            if (gr >= M) gr = M - 1;
            gl_lds16(A + (size_t)gr * aStride + kt + k8, (void*)&lds[buf][cb * 8]);
        }
#pragma unroll
        for (int p = 0; p < 2; ++p) {
            int cb = p * 256 + w * 64;
            int c = cb + lane;
            int r = c >> 2;
            int k8 = (c & 3) * 8;
            gl_lds16(Bw + (size_t)(tn + r) * bStride + kt + k8,
                     (void*)&lds[buf][BM * BK + cb * 8]);
        }
    };
    stage(0, 0);
    for (int t = 0; t < NT; ++t) {
        __syncthreads();
        if (t + 1 < NT) stage((t + 1) & 1, t + 1);
        const short* Ab = &lds[t & 1][0];
        const short* Bb = &lds[t & 1][BM * BK];
        int ko = (lane >> 4) * 8;
        int rr = lane & 15;
        bf16x8 af[MF], bfr[4];
#pragma unroll
        for (int m = 0; m < MF; ++m)
            af[m] = *(const bf16x8*)&Ab[(wr * (MF * 16) + m * 16 + rr) * BK + ko];
#pragma unroll
        for (int n = 0; n < 4; ++n)
            bfr[n] = *(const bf16x8*)&Bb[(wc * 64 + n * 16 + rr) * BK + ko];
#pragma unroll
        for (int m = 0; m < MF; ++m)
#pragma unroll
            for (int n = 0; n < 4; ++n)
                acc[m][n] = __builtin_amdgcn_mfma_f32_16x16x32_bf16(af[m], bfr[n],
                                                                    acc[m][n], 0, 0, 0);
    }
#pragma unroll
    for (int m = 0; m < MF; ++m) {
#pragma unroll
        for (int n = 0; n < 4; ++n) {
            int col = tn + wc * 64 + n * 16 + (lane & 15);
            float bsv = bias ? bias[col] : 0.f;
#pragma unroll
            for (int r = 0; r < 4; ++r) {
                int rowi = tm + wr * (MF * 16) + m * 16 + (lane >> 4) * 4 + r;
                if (rowi < M) C[(size_t)rowi * N + col] = acc[m][n][r] + bsv;
            }
        }
    }
}

extern "C" void kernel_launch(void* const* d_in, const int* in_sizes, int n_in,
                              void* d_out, int out_size, void* d_ws, size_t ws_size,
                              hipStream_t stream) {
    const float* x_in       = (const float*)d_in[0];
    const float* workspace  = (const float*)d_in[1];
    const float* compete_w  = (const float*)d_in[2];
    const float* compete_b  = (const float*)d_in[3];
    const float* write_w    = (const float*)d_in[4];
    const float* write_b    = (const float*)d_in[5];
    const float* in_proj_w  = (const float*)d_in[6];
    const float* in_proj_b  = (const float*)d_in[7];
    const float* out_proj_w = (const float*)d_in[8];
    const float* out_proj_b = (const float*)d_in[9];
    const float* norm_pre_w  = (const float*)d_in[12];
    const float* norm_post_w = (const float*)d_in[13];
    float* xout = (float*)d_out;

    char* base = (char*)d_ws;
    size_t off = 0;
    auto alloc = [&](size_t bytes) {
        void* p = base + off;
        off += (bytes + 255) & ~(size_t)255;
        return p;
    };
    ushort* xb      = (ushort*)alloc((size_t)BL * D * 2);
    float*  qbuf    = (float*) alloc((size_t)BL * D * 4);     // x_b (f32)
    float*  logits  = (float*) alloc((size_t)BATCH * NSLOT * LSEQ * 4);
    ushort* xbar    = (ushort*)alloc((size_t)BATCH * NSLOT * D * 2);
    float*  written = (float*) alloc((size_t)BATCH * NSLOT * D * 4);
    float*  wsbuf   = (float*) alloc((size_t)BATCH * NSLOT * D * 4);
    ushort* wsb     = (ushort*)alloc((size_t)BATCH * NSLOT * D * 2);
    ushort* ipb     = (ushort*)alloc((size_t)3 * D * D * 2);
    ushort* wob     = (ushort*)alloc((size_t)D * D * 2);
    ushort* wwb     = (ushort*)alloc((size_t)D * D * 2);
    ushort* wqt     = (ushort*)alloc((size_t)D * D * 2);      // Wq^T bf16
    ushort* kb16    = (ushort*)alloc((size_t)BATCH * NHEAD * NSLOT * HDIM * 2);
    ushort* vb16    = (ushort*)alloc((size_t)BATCH * NHEAD * NSLOT * HDIM * 2);
    ushort* ktil    = (ushort*)alloc((size_t)BATCH * 512 * D * 2);   // K~ rows b*512+hs
    ushort* wtilT   = (ushort*)alloc((size_t)D * BATCH * 512 * 2);   // W~^T rows j
    float*  qlog    = (float*) alloc((size_t)2 * BL * 512 * 4);      // 2 K-split planes
    ushort* aatt    = (ushort*)alloc((size_t)BL * 512 * 2);
    float*  cbias   = (float*) alloc((size_t)BATCH * 512 * 4);
    (void)ws_size; (void)in_sizes; (void)n_in; (void)out_size;

    conv_bf16_kernel<<<2048, 256, 0, stream>>>((const float4*)in_proj_w, ipb, 3 * D * D / 4);
    conv_bf16_kernel<<<2048, 256, 0, stream>>>((const float4*)out_proj_w, wob, D * D / 4);
    conv_bf16_kernel<<<2048, 256, 0, stream>>>((const float4*)write_w, wwb, D * D / 4);
    conv_bf16_kernel<<<2048, 256, 0, stream>>>((const float4*)x_in, xb, BL * D / 4);
    transpose_bf16_kernel<<<1024, 256, 0, stream>>>(ipb, wqt);   // Wq^T (q rows 0..D)

    for (int it = 0; it < 2; ++it) {
        const float* xs = it ? (const float*)xout : x_in;
        logits_kernel<<<BL / 4, 256, 0, stream>>>(xs, compete_w, compete_b, norm_pre_w,
                                                  logits);
        topk_xbar_kernel<<<BATCH * NSLOT, 256, 0, stream>>>(logits, xs, xbar);
        // written = xbar @ wwb^T + write_b   (64x2048, K=2048) — 512 waves
        gemm_tiny<0><<<128, 256, 0, stream>>>(xbar, wwb, write_b, written,
                                              BATCH * NSLOT, D, D,
                                              (ushort*)nullptr, (ushort*)nullptr);
        ws_update_kernel<<<BATCH * NSLOT, 256, 0, stream>>>(written, wsbuf, workspace,
                                                            it == 0 ? 1 : 0, norm_post_w,
                                                            wsbuf, wsb);
        // kv = wsb @ Wkv^T + bkv  (64x4096, K=2048) — 1024 waves, scatter to kb/vb
        gemm_tiny<1><<<256, 256, 0, stream>>>(wsb, ipb + (size_t)D * D, in_proj_b + D,
                                              (float*)nullptr, BATCH * NSLOT, 2 * D, D,
                                              kb16, vb16);
        cbias_kernel<<<8, 256, 0, stream>>>(kb16, in_proj_b, cbias);
        grouped16_kernel<0><<<1024, 256, 0, stream>>>(kb16, wqt, ktil);
        grouped16_kernel<1><<<1024, 256, 0, stream>>>(vb16, wob, wtilT);
        // qlog[z][l, hs] = xb[l, zK:zK+1024] . K~[b,hs, zK:zK+1024]  (split-K=2)
        gemm_bt<64><<<dim3(512 / 128, BL / 64, 2), 256, 0, stream>>>(
            xb, ktil, (const float*)nullptr, qlog, BL, 512, D / 2,
            (size_t)512 * D, D, D, D / 2, D / 2, (size_t)BL * 512);
        attn_sm_kernel<<<BL / 8, 256, 0, stream>>>(qlog, cbias, aatt);
        // x_b[l, j] = sum_hs aatt[l,hs] * W~T[j, b*512+hs] + out_proj_b[j]
        gemm_bt<64><<<dim3(D / 128, BL / 64), 256, 0, stream>>>(
            aatt, wtilT, out_proj_b, qbuf, BL, D, 512,
            (size_t)512, D, 512, 0, 0, 0);
        resid_rms_kernel<<<BL, 256, 0, stream>>>(xs, qbuf, norm_post_w, xout, xb);
    }
}